// Round 5
// baseline (578.517 us; speedup 1.0000x reference)
//
#include <hip/hip_runtime.h>
#include <hip/hip_bf16.h>
#include <cstdint>
#include <cmath>

#define DIM 4096
#define NH 32
#define NKV 8
#define HD 128
#define S_LEN 2048
#define KVD (NKV * HD)   // 1024
#define QS 6144          // fused qkv row stride
#define SCALE 0.08838834764831845f

typedef __attribute__((ext_vector_type(4))) float f32x4;
typedef __attribute__((ext_vector_type(8))) short short8;

__device__ __forceinline__ short f2bf(float f) {
  union { float f; uint32_t u; } v; v.f = f;
  uint32_t u = v.u;
  u += 0x7fffu + ((u >> 16) & 1u);
  return (short)(u >> 16);
}
__device__ __forceinline__ float bf2f(short b) {
  union { uint32_t u; float f; } v; v.u = ((uint32_t)(uint16_t)b) << 16;
  return v.f;
}

__device__ __forceinline__ void async16(const void* g, void* l) {
  __builtin_amdgcn_global_load_lds(
      (__attribute__((address_space(1))) void*)(g),
      (__attribute__((address_space(3))) void*)(l), 16, 0, 0);
}

// ---------------- small prep kernels ----------------

__global__ void rope_tables_k(float* __restrict__ ct, float* __restrict__ st) {
  const int i = blockIdx.x * blockDim.x + threadIdx.x;
  if (i >= S_LEN * 64) return;
  const int s = i >> 6, d = i & 63;
  const float inv = powf(10000.0f, -(float)(2 * d) / 128.0f);
  const float fr = (float)s * inv;
  ct[i] = cosf(fr);
  st[i] = sinf(fr);
}

__global__ void cast_f32_bf16_k(const float* __restrict__ in, short* __restrict__ out, int n4) {
  const int i = blockIdx.x * blockDim.x + threadIdx.x;
  if (i >= n4) return;
  const float4 v = ((const float4*)in)[i];
  short4 o;
  o.x = f2bf(v.x); o.y = f2bf(v.y); o.z = f2bf(v.z); o.w = f2bf(v.w);
  ((short4*)out)[i] = o;
}

// w: [K][N] f32 row-major  ->  wt: [N][K] bf16 row-major
__global__ void transpose_cast_k(const float* __restrict__ wsrc, short* __restrict__ wt,
                                 int K, int N) {
  __shared__ float tile[32][33];
  const int tx = threadIdx.x, ty = threadIdx.y;
  const int c0 = blockIdx.x * 32, r0 = blockIdx.y * 32;
#pragma unroll
  for (int j = 0; j < 4; ++j)
    tile[ty + j * 8][tx] = wsrc[(size_t)(r0 + ty + j * 8) * N + c0 + tx];
  __syncthreads();
#pragma unroll
  for (int j = 0; j < 4; ++j)
    wt[(size_t)(c0 + ty + j * 8) * K + r0 + tx] = f2bf(tile[tx][ty + j * 8]);
}

// bf16 transpose: in [R][C] (row stride ldi) -> out [C][R]
__global__ void transpose_bf16_k(const short* __restrict__ in, short* __restrict__ out,
                                 int R, int C, int ldi) {
  __shared__ short tile[32][33];
  const int tx = threadIdx.x, ty = threadIdx.y;
  const int c0 = blockIdx.x * 32, r0 = blockIdx.y * 32;
#pragma unroll
  for (int j = 0; j < 4; ++j)
    tile[ty + j * 8][tx] = in[(size_t)(r0 + ty + j * 8) * ldi + c0 + tx];
  __syncthreads();
#pragma unroll
  for (int j = 0; j < 4; ++j)
    out[(size_t)(c0 + ty + j * 8) * R + r0 + tx] = tile[tx][ty + j * 8];
}

// in-place RoPE on bf16 [S][*] with row stride ld; thread handles (d, d+64) pair
__global__ void rope_apply_k(short* __restrict__ xq, int ld, const float* __restrict__ ct,
                             const float* __restrict__ st, int nheads) {
  const int i = blockIdx.x * blockDim.x + threadIdx.x;
  const int total = S_LEN * nheads * 64;
  if (i >= total) return;
  const int d = i & 63;
  const int t = i >> 6;
  const int hh = t % nheads;
  const int s = t / nheads;
  short* p = xq + (size_t)s * ld + hh * HD + d;
  const float x1 = bf2f(p[0]);
  const float x2 = bf2f(p[64]);
  const float c = ct[(s << 6) + d];
  const float sn = st[(s << 6) + d];
  p[0]  = f2bf(x1 * c - x2 * sn);
  p[64] = f2bf(x2 * c + x1 * sn);
}

// ---------------- m201-style 256x256 8-phase GEMM (bf16 out) ----------------
// 8 waves (2M x 4N), per-wave C = 128x64. BK=64, dbuf LDS 128KB, XOR swizzle.
// Per phase: {ds_read next-phase frags (4 or 8 b128) | stage 1 half-tile (2 gl)
//  | vmcnt(6) | s_barrier | lgkmcnt(0) | setprio1 | 16 MFMA | setprio0 | s_barrier}.
// Stage->read flight = 4 phases; vmcnt(6) at phase i gates phase i+1's read.

#define PH(RD, ST, MF)                                         \
  do {                                                         \
    RD; ST;                                                    \
    asm volatile("s_waitcnt vmcnt(6)" ::: "memory");           \
    __builtin_amdgcn_s_barrier();                              \
    asm volatile("s_waitcnt lgkmcnt(0)" ::: "memory");         \
    __builtin_amdgcn_s_setprio(1);                             \
    MF;                                                        \
    __builtin_amdgcn_s_setprio(0);                             \
    __builtin_amdgcn_s_barrier();                              \
  } while (0)

#define PHX(RD, ST, VW, MF)                                    \
  do {                                                         \
    RD; ST;                                                    \
    VW;                                                        \
    __builtin_amdgcn_s_barrier();                              \
    asm volatile("s_waitcnt lgkmcnt(0)" ::: "memory");         \
    __builtin_amdgcn_s_setprio(1);                             \
    MF;                                                        \
    __builtin_amdgcn_s_setprio(0);                             \
    __builtin_amdgcn_s_barrier();                              \
  } while (0)

__global__ __launch_bounds__(512, 2) void gemm8p_k(
    const short* __restrict__ A, const short* __restrict__ BT,
    short* __restrict__ C, int M, int N, int K) {
  __shared__ __attribute__((aligned(16))) short lds[2][2][2][128 * 64];
  const int tid = threadIdx.x;
  const int l = tid & 63, w = tid >> 6;
  const int wr = w >> 2, wc = w & 3;
  const int lrow = l & 15, lg = l >> 4;
  const int brow0 = (wc & 1) * 64;

  int bid = blockIdx.x;
  const int cpx = gridDim.x >> 3;
  bid = (bid & 7) * cpx + (bid >> 3);
  const int ntn = N >> 8;
  const int m0 = (bid / ntn) << 8;
  const int n0 = (bid % ntn) << 8;

  // stage one half-tile (128 rows x 64 k) of tile tau into buf tau&1
  auto stageH = [&](int tau, int ab, int h) {
    const short* src = ab ? BT : A;
    const int base = (ab ? n0 : m0) + h * 128;
    short* dst = &lds[tau & 1][ab][h][0];
    const int k0 = tau << 6;
    const int r0 = tid >> 3;
    const int js = (tid & 7) ^ (r0 & 7);
    async16(src + (size_t)(base + r0) * K + k0 + js * 8, dst + tid * 8);
    async16(src + (size_t)(base + 64 + r0) * K + k0 + js * 8, dst + (512 + tid) * 8);
  };
  auto ldA = [&](short8 (&dst)[4][2], int b, int rh) {
    const short* Ah = &lds[b][0][wr][0];
#pragma unroll
    for (int mi = 0; mi < 4; ++mi) {
      const int row = rh * 64 + mi * 16 + lrow;
#pragma unroll
      for (int kk = 0; kk < 2; ++kk)
        dst[mi][kk] = *(const short8*)(Ah + row * 64 + (((kk * 4 + lg) ^ (row & 7)) << 3));
    }
  };
  auto ldB = [&](short8 (&dst)[2][2], int b, int ch) {
    const short* Bh = &lds[b][1][wc >> 1][0];
#pragma unroll
    for (int ni = 0; ni < 2; ++ni) {
      const int row = brow0 + ch * 32 + ni * 16 + lrow;
#pragma unroll
      for (int kk = 0; kk < 2; ++kk)
        dst[ni][kk] = *(const short8*)(Bh + row * 64 + (((kk * 4 + lg) ^ (row & 7)) << 3));
    }
  };

  f32x4 acc[8][4] = {};
  auto quad = [&](int mr0, short8 (&Af)[4][2], int nc0, short8 (&Bf)[2][2]) {
#pragma unroll
    for (int kk = 0; kk < 2; ++kk)
#pragma unroll
      for (int mi = 0; mi < 4; ++mi)
#pragma unroll
        for (int ni = 0; ni < 2; ++ni)
          acc[mr0 + mi][nc0 + ni] = __builtin_amdgcn_mfma_f32_16x16x32_bf16(
              Af[mi][kk], Bf[ni][kk], acc[mr0 + mi][nc0 + ni], 0, 0, 0);
  };

  short8 Aa[4][2], Ab[4][2], Bc0A[2][2], Bc0B[2][2], Bc1[2][2];

  // prologue: tile0 (all 4 halves) + tile1 h0 halves, oldest-first
  stageH(0, 1, 0); stageH(0, 0, 0); stageH(0, 1, 1); stageH(0, 0, 1);
  stageH(1, 1, 0); stageH(1, 0, 0);
  asm volatile("s_waitcnt vmcnt(4)" ::: "memory");  // tile0 fully landed
  __builtin_amdgcn_s_barrier();
  ldB(Bc0A, 0, 0);   // pre-reads for phase 0
  ldA(Aa, 0, 0);

  const int KT = K >> 6;  // even, >= 4
  for (int u = 0; u < (KT - 2) / 2; ++u) {
    const int e = 2 * u, o = e + 1;
    // tile e (buf0): quadrant order (r0c0)(r0c1)(r1c0)(r1c1)
    PH(ldB(Bc1, 0, 1),  stageH(o, 1, 1),     quad(0, Aa, 0, Bc0A));
    PH(ldA(Ab, 0, 1),   stageH(o, 0, 1),     quad(0, Aa, 2, Bc1));
    PH(ldB(Bc0B, 1, 0), stageH(e + 2, 1, 0), quad(4, Ab, 0, Bc0A));
    PH(ldA(Aa, 1, 0),   stageH(e + 2, 0, 0), quad(4, Ab, 2, Bc1));
    // tile o (buf1)
    PH(ldB(Bc1, 1, 1),  stageH(o + 1, 1, 1), quad(0, Aa, 0, Bc0B));
    PH(ldA(Ab, 1, 1),   stageH(o + 1, 0, 1), quad(0, Aa, 2, Bc1));
    PH(ldB(Bc0A, 0, 0), stageH(o + 2, 1, 0), quad(4, Ab, 0, Bc0B));
    PH(ldA(Aa, 0, 0),   stageH(o + 2, 0, 0), quad(4, Ab, 2, Bc1));
  }

  // final pair (KT-2: buf0, KT-1: buf1) with vmcnt drain ladder
  {
    const int O = KT - 1;
    PHX(ldB(Bc1, 0, 1),  stageH(O, 1, 1),
        asm volatile("s_waitcnt vmcnt(6)" ::: "memory"), quad(0, Aa, 0, Bc0A));
    PHX(ldA(Ab, 0, 1),   stageH(O, 0, 1),
        asm volatile("s_waitcnt vmcnt(4)" ::: "memory"), quad(0, Aa, 2, Bc1));
    PHX(ldB(Bc0B, 1, 0), (void)0,
        asm volatile("s_waitcnt vmcnt(2)" ::: "memory"), quad(4, Ab, 0, Bc0A));
    PHX(ldA(Aa, 1, 0),   (void)0,
        asm volatile("s_waitcnt vmcnt(0)" ::: "memory"), quad(4, Ab, 2, Bc1));
    // last tile: all data resident, no barriers needed
    ldB(Bc1, 1, 1);
    quad(0, Aa, 0, Bc0B);
    ldA(Ab, 1, 1);
    quad(0, Aa, 2, Bc1);
    quad(4, Ab, 0, Bc0B);
    quad(4, Ab, 2, Bc1);
  }

  // epilogue
  const int orow0 = m0 + wr * 128 + lg * 4;
  const int ocol0 = n0 + wc * 64 + lrow;
#pragma unroll
  for (int m = 0; m < 8; ++m)
#pragma unroll
    for (int n = 0; n < 4; ++n)
#pragma unroll
      for (int r = 0; r < 4; ++r)
        C[(size_t)(orow0 + m * 16 + r) * N + (ocol0 + n * 16)] = f2bf(acc[m][n][r]);
}

// ---------------- pipelined GEMM (WO: BM=128, NBUF=3, fp32 out) ----------------

template <int BM, int NBUF, int OUT_BF16>
__global__ __launch_bounds__(512, 2) void gemm_p(
    const short* __restrict__ A, const short* __restrict__ BT,
    void* __restrict__ Cv, int M, int N, int K) {
  constexpr int TILE = (BM + 256) * 64;
  constexpr int LA = BM / 64;
  constexpr int NP = BM / 64;
  __shared__ __attribute__((aligned(16))) short lds[NBUF][TILE];

  const int tid = threadIdx.x;
  const int w = tid >> 6, l = tid & 63;
  const int wr = w >> 2, wc = w & 3;
  const int lrow = l & 15, lg = l >> 4;

  int bid = blockIdx.x;
  const int cpx = gridDim.x >> 3;
  bid = (bid & 7) * cpx + (bid >> 3);
  const int ntn = N >> 8;
  const int m0 = (bid / ntn) * BM;
  const int n0 = (bid % ntn) << 8;

  auto stage = [&](int kt, int buf) {
    const int k0 = kt << 6;
    short* dst = &lds[buf][0];
#pragma unroll
    for (int it = 0; it < LA; ++it) {
      const int e = it * 512 + tid;
      const int row = e >> 3, j = e & 7;
      const int jsrc = j ^ (row & 7);
      async16(A + (size_t)(m0 + row) * K + k0 + jsrc * 8, dst + e * 8);
    }
#pragma unroll
    for (int it = 0; it < 4; ++it) {
      const int e = it * 512 + tid;
      const int row = e >> 3, j = e & 7;
      const int jsrc = j ^ (row & 7);
      async16(BT + (size_t)(n0 + row) * K + k0 + jsrc * 8, dst + BM * 64 + e * 8);
    }
  };

  auto vwait = [&](int J) {
    if constexpr (BM == 256) {
      if (J >= 1) asm volatile("s_waitcnt vmcnt(8)" ::: "memory");
      else        asm volatile("s_waitcnt vmcnt(0)" ::: "memory");
    } else {
      if (J >= 2)      asm volatile("s_waitcnt vmcnt(12)" ::: "memory");
      else if (J == 1) asm volatile("s_waitcnt vmcnt(6)" ::: "memory");
      else             asm volatile("s_waitcnt vmcnt(0)" ::: "memory");
    }
  };

  f32x4 acc[NP * 2][4] = {};

  const int KT = K >> 6;
#pragma unroll
  for (int t = 0; t < NBUF; ++t) stage(t, t);
  vwait(NBUF - 1);
  __builtin_amdgcn_s_barrier();

  for (int kt = 0; kt < KT; ++kt) {
    const int buf = kt % NBUF;
    const short* Ah = &lds[buf][0];
    const short* Bh = &lds[buf][BM * 64];
    short8 bfrag[2][4];

#pragma unroll
    for (int p = 0; p < NP; ++p) {
      short8 afrag[2][2];
#pragma unroll
      for (int mi = 0; mi < 2; ++mi) {
        const int row = wr * (BM / 2) + (p * 2 + mi) * 16 + lrow;
#pragma unroll
        for (int kk = 0; kk < 2; ++kk)
          afrag[mi][kk] =
              *(const short8*)(Ah + row * 64 + (((kk * 4 + lg) ^ (row & 7)) << 3));
      }
      if (p == 0) {
#pragma unroll
        for (int n = 0; n < 4; ++n) {
          const int row = wc * 64 + n * 16 + lrow;
#pragma unroll
          for (int kk = 0; kk < 2; ++kk)
            bfrag[kk][n] =
                *(const short8*)(Bh + row * 64 + (((kk * 4 + lg) ^ (row & 7)) << 3));
        }
      }
      __builtin_amdgcn_s_barrier();
      asm volatile("s_waitcnt lgkmcnt(0)" ::: "memory");
      __builtin_amdgcn_s_setprio(1);
#pragma unroll
      for (int kk = 0; kk < 2; ++kk)
#pragma unroll
        for (int mi = 0; mi < 2; ++mi)
#pragma unroll
          for (int n = 0; n < 4; ++n)
            acc[p * 2 + mi][n] = __builtin_amdgcn_mfma_f32_16x16x32_bf16(
                afrag[mi][kk], bfrag[kk][n], acc[p * 2 + mi][n], 0, 0, 0);
      __builtin_amdgcn_s_setprio(0);
      __builtin_amdgcn_s_barrier();
    }
    if (kt + 1 < KT) {
      const int nst = kt + NBUF;
      if (nst < KT) stage(nst, buf);
      const int J = (nst < KT ? nst : KT - 1) - (kt + 1);
      vwait(J);
      __builtin_amdgcn_s_barrier();
    }
  }

  const int orow0 = m0 + wr * (BM / 2) + lg * 4;
  const int ocol0 = n0 + wc * 64 + lrow;
#pragma unroll
  for (int m = 0; m < NP * 2; ++m)
#pragma unroll
    for (int n = 0; n < 4; ++n)
#pragma unroll
      for (int r = 0; r < 4; ++r) {
        const size_t idx = (size_t)(orow0 + m * 16 + r) * N + (ocol0 + n * 16);
        if (OUT_BF16)
          ((short*)Cv)[idx] = f2bf(acc[m][n][r]);
        else
          ((float*)Cv)[idx] = acc[m][n][r];
      }
}

// ---------------- flash attention (causal, GQA 4:1) ----------------

__global__ __launch_bounds__(256, 2) void attn_k(
    const short* __restrict__ Q, const short* __restrict__ Kc,
    const short* __restrict__ VTg, short* __restrict__ O) {
  __shared__ __attribute__((aligned(16))) short Ks[2][64 * 128];
  __shared__ __attribute__((aligned(16))) short Vt[2][128 * 64];
  __shared__ __attribute__((aligned(16))) short Ps[4][32 * 64];

  const int tid = threadIdx.x;
  const int w = tid >> 6, l = tid & 63;
  const int lrow = l & 15, lg = l >> 4;

  int b = blockIdx.x, h, qt;
  if (b < 256) { h = b >> 3; qt = 15 - (b & 7); }
  else { b -= 256; h = b >> 3; qt = b & 7; }
  const int kvh = h >> 2;
  const int qb0 = qt * 128;
  const int qrow0 = qb0 + w * 32;
  const int nkt = 2 * qt + 2;

  short8 qf[2][4];
#pragma unroll
  for (int nq = 0; nq < 2; ++nq) {
    const short* qp = Q + (size_t)(qrow0 + nq * 16 + lrow) * QS + h * HD;
#pragma unroll
    for (int c = 0; c < 4; ++c) qf[nq][c] = *(const short8*)(qp + c * 32 + lg * 8);
  }

  f32x4 o_acc[2][8] = {};
  float m[2] = {-INFINITY, -INFINITY};
  float lsum[2] = {0.f, 0.f};

  auto stage = [&](int kb, int buf) {
    short* kd = Ks[buf];
    short* vd = Vt[buf];
#pragma unroll
    for (int it = 0; it < 4; ++it) {
      const int e = it * 256 + tid;
      const int row = e >> 4, j = e & 15;
      const int jsrc = (j & 8) | ((j ^ row) & 7);
      async16(Kc + (size_t)(kb + row) * QS + kvh * HD + jsrc * 8, kd + e * 8);
    }
#pragma unroll
    for (int it = 0; it < 4; ++it) {
      const int e = it * 256 + tid;
      const int d = e >> 3, j = e & 7;
      const int jsrc = (j ^ d) & 7;
      async16(VTg + (size_t)(kvh * HD + d) * S_LEN + kb + jsrc * 8, vd + e * 8);
    }
  };

  stage(0, 0);
  int cur = 0;

  for (int kt = 0; kt < nkt; ++kt) {
    __syncthreads();
    if (kt + 1 < nkt) stage((kt + 1) * 64, cur ^ 1);
    const int kb = kt * 64;

    if (kb <= qrow0 + 31) {
      const char* ks = (const char*)Ks[cur];
      const char* vt = (const char*)Vt[cur];
      char* psb = (char*)Ps[w];

      f32x4 stq[4][2] = {};
#pragma unroll
      for (int c = 0; c < 4; ++c) {
#pragma unroll
        for (int mk = 0; mk < 4; ++mk) {
          const short8 kf = *(const short8*)(
              ks + (mk * 16 + lrow) * 256 + (((c * 4 + lg) ^ (lrow & 7)) << 4));
          stq[mk][0] = __builtin_amdgcn_mfma_f32_16x16x32_bf16(kf, qf[0][c], stq[mk][0], 0, 0, 0);
          stq[mk][1] = __builtin_amdgcn_mfma_f32_16x16x32_bf16(kf, qf[1][c], stq[mk][1], 0, 0, 0);
        }
      }

      const bool needmask = (kb + 63 > qrow0);
#pragma unroll
      for (int mk = 0; mk < 4; ++mk)
#pragma unroll
        for (int nq = 0; nq < 2; ++nq)
#pragma unroll
          for (int r = 0; r < 4; ++r) {
            float v = stq[mk][nq][r] * SCALE;
            if (needmask && (kb + mk * 16 + lg * 4 + r > qrow0 + nq * 16 + lrow))
              v = -INFINITY;
            stq[mk][nq][r] = v;
          }

      float vmax[2];
#pragma unroll
      for (int nq = 0; nq < 2; ++nq) {
        float v = stq[0][nq][0];
#pragma unroll
        for (int mk = 0; mk < 4; ++mk)
#pragma unroll
          for (int r = 0; r < 4; ++r) v = fmaxf(v, stq[mk][nq][r]);
        v = fmaxf(v, __shfl_xor(v, 16));
        v = fmaxf(v, __shfl_xor(v, 32));
        vmax[nq] = v;
      }

      const int small = (vmax[0] <= m[0] + 8.0f) && (vmax[1] <= m[1] + 8.0f);
      if (!__all(small)) {
        float al[2];
#pragma unroll
        for (int nq = 0; nq < 2; ++nq) {
          const float mn = fmaxf(m[nq], vmax[nq]);
          al[nq] = __expf(m[nq] - mn);
          m[nq] = mn;
          lsum[nq] *= al[nq];
        }
#pragma unroll
        for (int mmq = 0; mmq < 2; ++mmq)
#pragma unroll
          for (int r = 0; r < 4; ++r) {
            const float a = __shfl(al[mmq], lg * 4 + r);
#pragma unroll
            for (int d = 0; d < 8; ++d) o_acc[mmq][d][r] *= a;
          }
      }

      float rs[2] = {0.f, 0.f};
#pragma unroll
      for (int nq = 0; nq < 2; ++nq) {
#pragma unroll
        for (int mk = 0; mk < 4; ++mk) {
          const float p0 = __expf(stq[mk][nq][0] - m[nq]);
          const float p1 = __expf(stq[mk][nq][1] - m[nq]);
          const float p2 = __expf(stq[mk][nq][2] - m[nq]);
          const float p3 = __expf(stq[mk][nq][3] - m[nq]);
          rs[nq] += (p0 + p1) + (p2 + p3);
          __hip_bfloat16 b0 = __float2bfloat16(p0), b1 = __float2bfloat16(p1);
          __hip_bfloat16 b2 = __float2bfloat16(p2), b3 = __float2bfloat16(p3);
          short4 pk;
          pk.x = *(short*)&b0; pk.y = *(short*)&b1; pk.z = *(short*)&b2; pk.w = *(short*)&b3;
          const int q = nq * 16 + lrow;
          *(short4*)(psb + q * 128 + ((mk * 32 + lg * 8) ^ ((q & 7) << 4))) = pk;
        }
        float r2 = rs[nq];
        r2 += __shfl_xor(r2, 16);
        r2 += __shfl_xor(r2, 32);
        lsum[nq] += r2;
      }

#pragma unroll
      for (int cc = 0; cc < 2; ++cc) {
        const int chunk = ((cc * 4 + lg) ^ (lrow & 7)) << 4;
        const short8 pa0 = *(const short8*)(psb + lrow * 128 + chunk);
        const short8 pa1 = *(const short8*)(psb + (16 + lrow) * 128 + chunk);
#pragma unroll
        for (int d = 0; d < 8; ++d) {
          const short8 vf = *(const short8*)(vt + (d * 16 + lrow) * 128 + chunk);
          o_acc[0][d] = __builtin_amdgcn_mfma_f32_16x16x32_bf16(pa0, vf, o_acc[0][d], 0, 0, 0);
          o_acc[1][d] = __builtin_amdgcn_mfma_f32_16x16x32_bf16(pa1, vf, o_acc[1][d], 0, 0, 0);
        }
      }
    }
    cur ^= 1;
  }

  float linv[2] = {1.0f / lsum[0], 1.0f / lsum[1]};
#pragma unroll
  for (int mmq = 0; mmq < 2; ++mmq)
#pragma unroll
    for (int r = 0; r < 4; ++r) {
      const float li = __shfl(linv[mmq], lg * 4 + r);
      short* op = O + (size_t)(qrow0 + mmq * 16 + lg * 4 + r) * DIM + h * HD;
#pragma unroll
      for (int d = 0; d < 8; ++d)
        op[d * 16 + lrow] = f2bf(o_acc[mmq][d][r] * li);
    }
}

// ---------------- launch ----------------

extern "C" void kernel_launch(void* const* d_in, const int* in_sizes, int n_in,
                              void* d_out, int out_size, void* d_ws, size_t ws_size,
                              hipStream_t stream) {
  const float* x  = (const float*)d_in[0];
  const float* wq = (const float*)d_in[1];
  const float* wk = (const float*)d_in[2];
  const float* wv = (const float*)d_in[3];
  const float* wo = (const float*)d_in[4];
  float* out = (float*)d_out;
  (void)in_sizes; (void)n_in; (void)out_size; (void)ws_size;

  char* ws = (char*)d_ws;
  size_t off = 0;
  auto alloc = [&](size_t bytes) -> void* {
    void* p = ws + off;
    off += (bytes + 255) & ~(size_t)255;
    return p;
  };
  short* xb     = (short*)alloc((size_t)S_LEN * DIM * 2);
  short* wqkvT  = (short*)alloc((size_t)QS * DIM * 2);     // [6144][4096]
  short* woT    = (short*)alloc((size_t)DIM * DIM * 2);
  short* qkv    = (short*)alloc((size_t)S_LEN * QS * 2);   // [2048][6144]
  short* vtg    = (short*)alloc((size_t)KVD * S_LEN * 2);  // [1024][2048]
  short* ao     = (short*)alloc((size_t)S_LEN * DIM * 2);
  float* ct     = (float*)alloc((size_t)S_LEN * 64 * 4);
  float* st     = (float*)alloc((size_t)S_LEN * 64 * 4);

  rope_tables_k<<<(S_LEN * 64) / 256, 256, 0, stream>>>(ct, st);
  cast_f32_bf16_k<<<(S_LEN * DIM / 4) / 256, 256, 0, stream>>>(x, xb, S_LEN * DIM / 4);
  transpose_cast_k<<<dim3(DIM / 32, DIM / 32), dim3(32, 8), 0, stream>>>(wq, wqkvT, DIM, DIM);
  transpose_cast_k<<<dim3(KVD / 32, DIM / 32), dim3(32, 8), 0, stream>>>(
      wk, wqkvT + (size_t)4096 * DIM, DIM, KVD);
  transpose_cast_k<<<dim3(KVD / 32, DIM / 32), dim3(32, 8), 0, stream>>>(
      wv, wqkvT + (size_t)5120 * DIM, DIM, KVD);
  transpose_cast_k<<<dim3(DIM / 32, DIM / 32), dim3(32, 8), 0, stream>>>(wo, woT, DIM, DIM);

  // fused QKV projection: [2048][6144], m201 8-phase 256x256 tiles, 192 blocks
  gemm8p_k<<<dim3((S_LEN / 256) * (QS / 256)), 512, 0, stream>>>(
      xb, wqkvT, qkv, S_LEN, QS, DIM);

  rope_apply_k<<<(S_LEN * NH * 64) / 256, 256, 0, stream>>>(qkv, QS, ct, st, NH);
  rope_apply_k<<<(S_LEN * NKV * 64) / 256, 256, 0, stream>>>(qkv + 4096, QS, ct, st, NKV);

  transpose_bf16_k<<<dim3(KVD / 32, S_LEN / 32), dim3(32, 8), 0, stream>>>(
      qkv + 5120, vtg, S_LEN, KVD, QS);

  attn_k<<<dim3(512), 256, 0, stream>>>(qkv, qkv + 4096, vtg, ao);

  // output projection: 128x256 tiles -> 256 blocks (full machine), depth-3 pipeline
  gemm_p<128, 3, 0><<<dim3((S_LEN / 128) * (DIM / 256)), 512, 0, stream>>>(
      ao, woT, out, S_LEN, DIM, DIM);
}

// Round 7
// 363.816 us; speedup vs baseline: 1.5901x; 1.5901x over previous
//
#include <hip/hip_runtime.h>
#include <hip/hip_bf16.h>
#include <cstdint>
#include <cmath>

#define DIM 4096
#define NH 32
#define NKV 8
#define HD 128
#define S_LEN 2048
#define KVD (NKV * HD)   // 1024
#define QS 6144          // fused qkv row stride
#define SCALE 0.08838834764831845f

typedef __attribute__((ext_vector_type(4))) float f32x4;
typedef __attribute__((ext_vector_type(8))) short short8;

__device__ __forceinline__ short f2bf(float f) {
  union { float f; uint32_t u; } v; v.f = f;
  uint32_t u = v.u;
  u += 0x7fffu + ((u >> 16) & 1u);
  return (short)(u >> 16);
}
__device__ __forceinline__ float bf2f(short b) {
  union { uint32_t u; float f; } v; v.u = ((uint32_t)(uint16_t)b) << 16;
  return v.f;
}

__device__ __forceinline__ void async16(const void* g, void* l) {
  __builtin_amdgcn_global_load_lds(
      (__attribute__((address_space(1))) void*)(g),
      (__attribute__((address_space(3))) void*)(l), 16, 0, 0);
}

// ---------------- small prep kernels ----------------

__global__ void rope_tables_k(float* __restrict__ ct, float* __restrict__ st) {
  const int i = blockIdx.x * blockDim.x + threadIdx.x;
  if (i >= S_LEN * 64) return;
  const int s = i >> 6, d = i & 63;
  const float inv = powf(10000.0f, -(float)(2 * d) / 128.0f);
  const float fr = (float)s * inv;
  ct[i] = cosf(fr);
  st[i] = sinf(fr);
}

__global__ void cast_f32_bf16_k(const float* __restrict__ in, short* __restrict__ out, int n4) {
  const int i = blockIdx.x * blockDim.x + threadIdx.x;
  if (i >= n4) return;
  const float4 v = ((const float4*)in)[i];
  short4 o;
  o.x = f2bf(v.x); o.y = f2bf(v.y); o.z = f2bf(v.z); o.w = f2bf(v.w);
  ((short4*)out)[i] = o;
}

// w: [K][N] f32 row-major  ->  wt: [N][K] bf16 row-major
__global__ void transpose_cast_k(const float* __restrict__ wsrc, short* __restrict__ wt,
                                 int K, int N) {
  __shared__ float tile[32][33];
  const int tx = threadIdx.x, ty = threadIdx.y;
  const int c0 = blockIdx.x * 32, r0 = blockIdx.y * 32;
#pragma unroll
  for (int j = 0; j < 4; ++j)
    tile[ty + j * 8][tx] = wsrc[(size_t)(r0 + ty + j * 8) * N + c0 + tx];
  __syncthreads();
#pragma unroll
  for (int j = 0; j < 4; ++j)
    wt[(size_t)(c0 + ty + j * 8) * K + r0 + tx] = f2bf(tile[tx][ty + j * 8]);
}

// bf16 transpose: in [R][C] (row stride ldi) -> out [C][R]
__global__ void transpose_bf16_k(const short* __restrict__ in, short* __restrict__ out,
                                 int R, int C, int ldi) {
  __shared__ short tile[32][33];
  const int tx = threadIdx.x, ty = threadIdx.y;
  const int c0 = blockIdx.x * 32, r0 = blockIdx.y * 32;
#pragma unroll
  for (int j = 0; j < 4; ++j)
    tile[ty + j * 8][tx] = in[(size_t)(r0 + ty + j * 8) * ldi + c0 + tx];
  __syncthreads();
#pragma unroll
  for (int j = 0; j < 4; ++j)
    out[(size_t)(c0 + ty + j * 8) * R + r0 + tx] = tile[tx][ty + j * 8];
}

// in-place RoPE on bf16 [S][*] with row stride ld; thread handles (d, d+64) pair
__global__ void rope_apply_k(short* __restrict__ xq, int ld, const float* __restrict__ ct,
                             const float* __restrict__ st, int nheads) {
  const int i = blockIdx.x * blockDim.x + threadIdx.x;
  const int total = S_LEN * nheads * 64;
  if (i >= total) return;
  const int d = i & 63;
  const int t = i >> 6;
  const int hh = t % nheads;
  const int s = t / nheads;
  short* p = xq + (size_t)s * ld + hh * HD + d;
  const float x1 = bf2f(p[0]);
  const float x2 = bf2f(p[64]);
  const float c = ct[(s << 6) + d];
  const float sn = st[(s << 6) + d];
  p[0]  = f2bf(x1 * c - x2 * sn);
  p[64] = f2bf(x2 * c + x1 * sn);
}

// ---------------- m201-style 256x256 8-phase GEMM (bf16 out) ----------------
// 8 waves (2M x 4N), per-wave C = 128x64, BK=64, dbuf LDS (128KB), XOR swizzle.
// Quadrants p0:A0B0 p1:A1B0 p2:A0B1 p3:A1B1. Single-buffered frag sets:
//   p0 RD A1(t), p1 RD B1(t), p2 RD B0(t+1), p3 RD A0(t+1)   (4 sets = 96 VGPR)
// Stage: p2 -> B halves of t+2 (4 gl), p3 -> A halves of t+2. vmcnt(4) uniform.
// Ledger (steady): B(t+1) forced complete at (t-1).p3; A(t+1) at t.p2 (because
// B(t+2)'s 4 loads are also outstanding there). TAIL: at t=KT-2.p2 no new stage
// is issued, so vmcnt(4) would NOT drain A(KT-1) -> use vmcnt(0) there (the R6
// race). Last tile is pure-register: lgkmcnt + sched_barrier only.

#define RD_A(DST, BASE, SUB)                                                     \
  do {                                                                           \
    _Pragma("unroll") for (int mi_ = 0; mi_ < 4; ++mi_) {                        \
      _Pragma("unroll") for (int kk_ = 0; kk_ < 2; ++kk_)                        \
        DST[mi_][kk_] = *(const short8*)((BASE) +                                \
            ((SUB) * 64 + mi_ * 16 + lrow) * 64 + cofs[kk_]);                    \
    }                                                                            \
  } while (0)

#define RD_B(DST, BASE, SUB)                                                     \
  do {                                                                           \
    _Pragma("unroll") for (int ni_ = 0; ni_ < 2; ++ni_) {                        \
      _Pragma("unroll") for (int kk_ = 0; kk_ < 2; ++kk_)                        \
        DST[ni_][kk_] = *(const short8*)((BASE) +                                \
            (brow + (SUB) * 32 + ni_ * 16 + lrow) * 64 + cofs[kk_]);             \
    }                                                                            \
  } while (0)

// stage BOTH halves (256 rows x 64 k) of operand AB for tile TAU (4 loads/thread)
#define ST_AB(AB, TAU)                                                           \
  do {                                                                           \
    const int k0_ = (TAU) << 6;                                                  \
    const short* src_ = (AB) ? BT : A;                                           \
    const int b0_ = (AB) ? n0 : m0;                                              \
    short* dst_ = &lds[(TAU) & 1][AB][0][0];                                     \
    async16(src_ + (size_t)(b0_ + r0s) * K + k0_ + jss * 8, dst_ + tid * 8);     \
    async16(src_ + (size_t)(b0_ + 64 + r0s) * K + k0_ + jss * 8,                 \
            dst_ + (512 + tid) * 8);                                             \
    async16(src_ + (size_t)(b0_ + 128 + r0s) * K + k0_ + jss * 8,                \
            dst_ + (1024 + tid) * 8);                                            \
    async16(src_ + (size_t)(b0_ + 192 + r0s) * K + k0_ + jss * 8,                \
            dst_ + (1536 + tid) * 8);                                            \
  } while (0)

#define QUAD(M0, AF, N0, BF)                                                     \
  do {                                                                           \
    _Pragma("unroll") for (int kk_ = 0; kk_ < 2; ++kk_)                          \
      _Pragma("unroll") for (int mi_ = 0; mi_ < 4; ++mi_)                        \
        _Pragma("unroll") for (int ni_ = 0; ni_ < 2; ++ni_)                      \
          acc[(M0) + mi_][(N0) + ni_] = __builtin_amdgcn_mfma_f32_16x16x32_bf16( \
              AF[mi_][kk_], BF[ni_][kk_], acc[(M0) + mi_][(N0) + ni_], 0, 0, 0); \
  } while (0)

#define PH_SYNC_N(VM)                                            \
  asm volatile("s_waitcnt vmcnt(" #VM ")" ::: "memory");         \
  __builtin_amdgcn_s_barrier();                                  \
  asm volatile("s_waitcnt lgkmcnt(0)" ::: "memory");             \
  __builtin_amdgcn_sched_barrier(0);                             \
  __builtin_amdgcn_s_setprio(1)

#define PH_END()                                                 \
  __builtin_amdgcn_s_setprio(0);                                 \
  __builtin_amdgcn_sched_barrier(0);                             \
  __builtin_amdgcn_s_barrier()

__global__ __launch_bounds__(512, 2) void gemm8p_k(
    const short* __restrict__ A, const short* __restrict__ BT,
    short* __restrict__ C, int M, int N, int K) {
  __shared__ __attribute__((aligned(16))) short lds[2][2][2][128 * 64];
  const int tid = threadIdx.x;
  const int l = tid & 63, w = tid >> 6;
  const int wr = w >> 2, wc = w & 3;
  const int lrow = l & 15, lg = l >> 4;
  const int brow = (wc & 1) * 64;
  const int cofs[2] = {(lg ^ (lrow & 7)) << 3, ((4 + lg) ^ (lrow & 7)) << 3};
  const int r0s = tid >> 3;
  const int jss = (tid & 7) ^ (r0s & 7);

  int bid = blockIdx.x;
  const int cpx = gridDim.x >> 3;
  bid = (bid & 7) * cpx + (bid >> 3);
  const int ntn = N >> 8;
  const int m0 = (bid / ntn) << 8;
  const int n0 = (bid % ntn) << 8;

  f32x4 acc[8][4] = {};
  short8 A0f[4][2], A1f[4][2], B0f[2][2], B1f[2][2];

  // prologue: stage t0 (B,A) then t1 (B,A); wait t0; pre-read B0(0), A0(0)
  ST_AB(1, 0); ST_AB(0, 0); ST_AB(1, 1); ST_AB(0, 1);
  asm volatile("s_waitcnt vmcnt(8)" ::: "memory");
  __builtin_amdgcn_s_barrier();
  {
    const short* LB0 = &lds[0][1][wc >> 1][0];
    const short* LA0 = &lds[0][0][wr][0];
    RD_B(B0f, LB0, 0);
    RD_A(A0f, LA0, 0);
  }

  const int KT = K >> 6;  // >= 3
  // ---- main loop: steady schedule, stages tile tau+2 (always valid) ----
  for (int tau = 0; tau < KT - 2; ++tau) {
    const int c = tau & 1;
    const short* LA = &lds[c][0][wr][0];
    const short* LB = &lds[c][1][wc >> 1][0];
    const short* LAn = &lds[c ^ 1][0][wr][0];
    const short* LBn = &lds[c ^ 1][1][wc >> 1][0];

    RD_A(A1f, LA, 1);
    PH_SYNC_N(4);
    QUAD(0, A0f, 0, B0f);
    PH_END();

    RD_B(B1f, LB, 1);
    PH_SYNC_N(4);
    QUAD(4, A1f, 0, B0f);
    PH_END();

    RD_B(B0f, LBn, 0);
    ST_AB(1, tau + 2);
    PH_SYNC_N(4);
    QUAD(0, A0f, 2, B1f);
    PH_END();

    RD_A(A0f, LAn, 0);
    ST_AB(0, tau + 2);
    PH_SYNC_N(4);
    QUAD(4, A1f, 2, B1f);
    PH_END();
  }

  // ---- tile KT-2: no more staging; drain A(KT-1) at p2 with vmcnt(0) ----
  {
    const int c = (KT - 2) & 1;
    const short* LA = &lds[c][0][wr][0];
    const short* LB = &lds[c][1][wc >> 1][0];
    const short* LAn = &lds[c ^ 1][0][wr][0];
    const short* LBn = &lds[c ^ 1][1][wc >> 1][0];

    RD_A(A1f, LA, 1);
    PH_SYNC_N(4);
    QUAD(0, A0f, 0, B0f);
    PH_END();

    RD_B(B1f, LB, 1);
    PH_SYNC_N(4);
    QUAD(4, A1f, 0, B0f);
    PH_END();

    RD_B(B0f, LBn, 0);
    PH_SYNC_N(0);            // forces A(KT-1) staging complete (R6's missing drain)
    QUAD(0, A0f, 2, B1f);
    PH_END();

    RD_A(A0f, LAn, 0);
    PH_SYNC_N(0);            // trivial (nothing outstanding), keeps barrier pairing
    QUAD(4, A1f, 2, B1f);
    PH_END();
  }

  // ---- tile KT-1: pure register compute, no LDS writes in flight ----
  {
    const int c = (KT - 1) & 1;
    const short* LA = &lds[c][0][wr][0];
    const short* LB = &lds[c][1][wc >> 1][0];
    RD_A(A1f, LA, 1);
    RD_B(B1f, LB, 1);
    asm volatile("s_waitcnt lgkmcnt(0)" ::: "memory");
    __builtin_amdgcn_sched_barrier(0);
    QUAD(0, A0f, 0, B0f);
    QUAD(4, A1f, 0, B0f);
    QUAD(0, A0f, 2, B1f);
    QUAD(4, A1f, 2, B1f);
  }

  // epilogue
  const int orow0 = m0 + wr * 128 + lg * 4;
  const int ocol0 = n0 + wc * 64 + lrow;
#pragma unroll
  for (int m = 0; m < 8; ++m)
#pragma unroll
    for (int n = 0; n < 4; ++n)
#pragma unroll
      for (int r = 0; r < 4; ++r)
        C[(size_t)(orow0 + m * 16 + r) * N + (ocol0 + n * 16)] = f2bf(acc[m][n][r]);
}

// ---------------- pipelined GEMM (WO: BM=128, NBUF=3, fp32 out) ----------------

template <int BM, int NBUF, int OUT_BF16>
__global__ __launch_bounds__(512, 2) void gemm_p(
    const short* __restrict__ A, const short* __restrict__ BT,
    void* __restrict__ Cv, int M, int N, int K) {
  constexpr int TILE = (BM + 256) * 64;
  constexpr int LA = BM / 64;
  constexpr int NP = BM / 64;
  __shared__ __attribute__((aligned(16))) short lds[NBUF][TILE];

  const int tid = threadIdx.x;
  const int w = tid >> 6, l = tid & 63;
  const int wr = w >> 2, wc = w & 3;
  const int lrow = l & 15, lg = l >> 4;

  int bid = blockIdx.x;
  const int cpx = gridDim.x >> 3;
  bid = (bid & 7) * cpx + (bid >> 3);
  const int ntn = N >> 8;
  const int m0 = (bid / ntn) * BM;
  const int n0 = (bid % ntn) << 8;

  auto stage = [&](int kt, int buf) {
    const int k0 = kt << 6;
    short* dst = &lds[buf][0];
#pragma unroll
    for (int it = 0; it < LA; ++it) {
      const int e = it * 512 + tid;
      const int row = e >> 3, j = e & 7;
      const int jsrc = j ^ (row & 7);
      async16(A + (size_t)(m0 + row) * K + k0 + jsrc * 8, dst + e * 8);
    }
#pragma unroll
    for (int it = 0; it < 4; ++it) {
      const int e = it * 512 + tid;
      const int row = e >> 3, j = e & 7;
      const int jsrc = j ^ (row & 7);
      async16(BT + (size_t)(n0 + row) * K + k0 + jsrc * 8, dst + BM * 64 + e * 8);
    }
  };

  auto vwait = [&](int J) {
    if constexpr (BM == 256) {
      if (J >= 1) asm volatile("s_waitcnt vmcnt(8)" ::: "memory");
      else        asm volatile("s_waitcnt vmcnt(0)" ::: "memory");
    } else {
      if (J >= 2)      asm volatile("s_waitcnt vmcnt(12)" ::: "memory");
      else if (J == 1) asm volatile("s_waitcnt vmcnt(6)" ::: "memory");
      else             asm volatile("s_waitcnt vmcnt(0)" ::: "memory");
    }
  };

  f32x4 acc[NP * 2][4] = {};

  const int KT = K >> 6;
#pragma unroll
  for (int t = 0; t < NBUF; ++t) stage(t, t);
  vwait(NBUF - 1);
  __builtin_amdgcn_s_barrier();

  for (int kt = 0; kt < KT; ++kt) {
    const int buf = kt % NBUF;
    const short* Ah = &lds[buf][0];
    const short* Bh = &lds[buf][BM * 64];
    short8 bfrag[2][4];

#pragma unroll
    for (int p = 0; p < NP; ++p) {
      short8 afrag[2][2];
#pragma unroll
      for (int mi = 0; mi < 2; ++mi) {
        const int row = wr * (BM / 2) + (p * 2 + mi) * 16 + lrow;
#pragma unroll
        for (int kk = 0; kk < 2; ++kk)
          afrag[mi][kk] =
              *(const short8*)(Ah + row * 64 + (((kk * 4 + lg) ^ (row & 7)) << 3));
      }
      if (p == 0) {
#pragma unroll
        for (int n = 0; n < 4; ++n) {
          const int row = wc * 64 + n * 16 + lrow;
#pragma unroll
          for (int kk = 0; kk < 2; ++kk)
            bfrag[kk][n] =
                *(const short8*)(Bh + row * 64 + (((kk * 4 + lg) ^ (row & 7)) << 3));
        }
      }
      __builtin_amdgcn_s_barrier();
      asm volatile("s_waitcnt lgkmcnt(0)" ::: "memory");
      __builtin_amdgcn_s_setprio(1);
#pragma unroll
      for (int kk = 0; kk < 2; ++kk)
#pragma unroll
        for (int mi = 0; mi < 2; ++mi)
#pragma unroll
          for (int n = 0; n < 4; ++n)
            acc[p * 2 + mi][n] = __builtin_amdgcn_mfma_f32_16x16x32_bf16(
                afrag[mi][kk], bfrag[kk][n], acc[p * 2 + mi][n], 0, 0, 0);
      __builtin_amdgcn_s_setprio(0);
      __builtin_amdgcn_s_barrier();
    }
    if (kt + 1 < KT) {
      const int nst = kt + NBUF;
      if (nst < KT) stage(nst, buf);
      const int J = (nst < KT ? nst : KT - 1) - (kt + 1);
      vwait(J);
      __builtin_amdgcn_s_barrier();
    }
  }

  const int orow0 = m0 + wr * (BM / 2) + lg * 4;
  const int ocol0 = n0 + wc * 64 + lrow;
#pragma unroll
  for (int m = 0; m < NP * 2; ++m)
#pragma unroll
    for (int n = 0; n < 4; ++n)
#pragma unroll
      for (int r = 0; r < 4; ++r) {
        const size_t idx = (size_t)(orow0 + m * 16 + r) * N + (ocol0 + n * 16);
        if (OUT_BF16)
          ((short*)Cv)[idx] = f2bf(acc[m][n][r]);
        else
          ((float*)Cv)[idx] = acc[m][n][r];
      }
}

// ---------------- flash attention (causal, GQA 4:1) ----------------

__global__ __launch_bounds__(256, 2) void attn_k(
    const short* __restrict__ Q, const short* __restrict__ Kc,
    const short* __restrict__ VTg, short* __restrict__ O) {
  __shared__ __attribute__((aligned(16))) short Ks[2][64 * 128];
  __shared__ __attribute__((aligned(16))) short Vt[2][128 * 64];
  __shared__ __attribute__((aligned(16))) short Ps[4][32 * 64];

  const int tid = threadIdx.x;
  const int w = tid >> 6, l = tid & 63;
  const int lrow = l & 15, lg = l >> 4;

  int b = blockIdx.x, h, qt;
  if (b < 256) { h = b >> 3; qt = 15 - (b & 7); }
  else { b -= 256; h = b >> 3; qt = b & 7; }
  const int kvh = h >> 2;
  const int qb0 = qt * 128;
  const int qrow0 = qb0 + w * 32;
  const int nkt = 2 * qt + 2;

  short8 qf[2][4];
#pragma unroll
  for (int nq = 0; nq < 2; ++nq) {
    const short* qp = Q + (size_t)(qrow0 + nq * 16 + lrow) * QS + h * HD;
#pragma unroll
    for (int c = 0; c < 4; ++c) qf[nq][c] = *(const short8*)(qp + c * 32 + lg * 8);
  }

  f32x4 o_acc[2][8] = {};
  float m[2] = {-INFINITY, -INFINITY};
  float lsum[2] = {0.f, 0.f};

  auto stage = [&](int kb, int buf) {
    short* kd = Ks[buf];
    short* vd = Vt[buf];
#pragma unroll
    for (int it = 0; it < 4; ++it) {
      const int e = it * 256 + tid;
      const int row = e >> 4, j = e & 15;
      const int jsrc = (j & 8) | ((j ^ row) & 7);
      async16(Kc + (size_t)(kb + row) * QS + kvh * HD + jsrc * 8, kd + e * 8);
    }
#pragma unroll
    for (int it = 0; it < 4; ++it) {
      const int e = it * 256 + tid;
      const int d = e >> 3, j = e & 7;
      const int jsrc = (j ^ d) & 7;
      async16(VTg + (size_t)(kvh * HD + d) * S_LEN + kb + jsrc * 8, vd + e * 8);
    }
  };

  stage(0, 0);
  int cur = 0;

  for (int kt = 0; kt < nkt; ++kt) {
    __syncthreads();
    if (kt + 1 < nkt) stage((kt + 1) * 64, cur ^ 1);
    const int kb = kt * 64;

    if (kb <= qrow0 + 31) {
      const char* ks = (const char*)Ks[cur];
      const char* vt = (const char*)Vt[cur];
      char* psb = (char*)Ps[w];

      f32x4 stq[4][2] = {};
#pragma unroll
      for (int c = 0; c < 4; ++c) {
#pragma unroll
        for (int mk = 0; mk < 4; ++mk) {
          const short8 kf = *(const short8*)(
              ks + (mk * 16 + lrow) * 256 + (((c * 4 + lg) ^ (lrow & 7)) << 4));
          stq[mk][0] = __builtin_amdgcn_mfma_f32_16x16x32_bf16(kf, qf[0][c], stq[mk][0], 0, 0, 0);
          stq[mk][1] = __builtin_amdgcn_mfma_f32_16x16x32_bf16(kf, qf[1][c], stq[mk][1], 0, 0, 0);
        }
      }

      const bool needmask = (kb + 63 > qrow0);
#pragma unroll
      for (int mk = 0; mk < 4; ++mk)
#pragma unroll
        for (int nq = 0; nq < 2; ++nq)
#pragma unroll
          for (int r = 0; r < 4; ++r) {
            float v = stq[mk][nq][r] * SCALE;
            if (needmask && (kb + mk * 16 + lg * 4 + r > qrow0 + nq * 16 + lrow))
              v = -INFINITY;
            stq[mk][nq][r] = v;
          }

      float vmax[2];
#pragma unroll
      for (int nq = 0; nq < 2; ++nq) {
        float v = stq[0][nq][0];
#pragma unroll
        for (int mk = 0; mk < 4; ++mk)
#pragma unroll
          for (int r = 0; r < 4; ++r) v = fmaxf(v, stq[mk][nq][r]);
        v = fmaxf(v, __shfl_xor(v, 16));
        v = fmaxf(v, __shfl_xor(v, 32));
        vmax[nq] = v;
      }

      const int small = (vmax[0] <= m[0] + 8.0f) && (vmax[1] <= m[1] + 8.0f);
      if (!__all(small)) {
        float al[2];
#pragma unroll
        for (int nq = 0; nq < 2; ++nq) {
          const float mn = fmaxf(m[nq], vmax[nq]);
          al[nq] = __expf(m[nq] - mn);
          m[nq] = mn;
          lsum[nq] *= al[nq];
        }
#pragma unroll
        for (int mmq = 0; mmq < 2; ++mmq)
#pragma unroll
          for (int r = 0; r < 4; ++r) {
            const float a = __shfl(al[mmq], lg * 4 + r);
#pragma unroll
            for (int d = 0; d < 8; ++d) o_acc[mmq][d][r] *= a;
          }
      }

      float rs[2] = {0.f, 0.f};
#pragma unroll
      for (int nq = 0; nq < 2; ++nq) {
#pragma unroll
        for (int mk = 0; mk < 4; ++mk) {
          const float p0 = __expf(stq[mk][nq][0] - m[nq]);
          const float p1 = __expf(stq[mk][nq][1] - m[nq]);
          const float p2 = __expf(stq[mk][nq][2] - m[nq]);
          const float p3 = __expf(stq[mk][nq][3] - m[nq]);
          rs[nq] += (p0 + p1) + (p2 + p3);
          __hip_bfloat16 b0 = __float2bfloat16(p0), b1 = __float2bfloat16(p1);
          __hip_bfloat16 b2 = __float2bfloat16(p2), b3 = __float2bfloat16(p3);
          short4 pk;
          pk.x = *(short*)&b0; pk.y = *(short*)&b1; pk.z = *(short*)&b2; pk.w = *(short*)&b3;
          const int q = nq * 16 + lrow;
          *(short4*)(psb + q * 128 + ((mk * 32 + lg * 8) ^ ((q & 7) << 4))) = pk;
        }
        float r2 = rs[nq];
        r2 += __shfl_xor(r2, 16);
        r2 += __shfl_xor(r2, 32);
        lsum[nq] += r2;
      }

#pragma unroll
      for (int cc = 0; cc < 2; ++cc) {
        const int chunk = ((cc * 4 + lg) ^ (lrow & 7)) << 4;
        const short8 pa0 = *(const short8*)(psb + lrow * 128 + chunk);
        const short8 pa1 = *(const short8*)(psb + (16 + lrow) * 128 + chunk);
#pragma unroll
        for (int d = 0; d < 8; ++d) {
          const short8 vf = *(const short8*)(vt + (d * 16 + lrow) * 128 + chunk);
          o_acc[0][d] = __builtin_amdgcn_mfma_f32_16x16x32_bf16(pa0, vf, o_acc[0][d], 0, 0, 0);
          o_acc[1][d] = __builtin_amdgcn_mfma_f32_16x16x32_bf16(pa1, vf, o_acc[1][d], 0, 0, 0);
        }
      }
    }
    cur ^= 1;
  }

  float linv[2] = {1.0f / lsum[0], 1.0f / lsum[1]};
#pragma unroll
  for (int mmq = 0; mmq < 2; ++mmq)
#pragma unroll
    for (int r = 0; r < 4; ++r) {
      const float li = __shfl(linv[mmq], lg * 4 + r);
      short* op = O + (size_t)(qrow0 + mmq * 16 + lg * 4 + r) * DIM + h * HD;
#pragma unroll
      for (int d = 0; d < 8; ++d)
        op[d * 16 + lrow] = f2bf(o_acc[mmq][d][r] * li);
    }
}

// ---------------- launch ----------------

extern "C" void kernel_launch(void* const* d_in, const int* in_sizes, int n_in,
                              void* d_out, int out_size, void* d_ws, size_t ws_size,
                              hipStream_t stream) {
  const float* x  = (const float*)d_in[0];
  const float* wq = (const float*)d_in[1];
  const float* wk = (const float*)d_in[2];
  const float* wv = (const float*)d_in[3];
  const float* wo = (const float*)d_in[4];
  float* out = (float*)d_out;
  (void)in_sizes; (void)n_in; (void)out_size; (void)ws_size;

  char* ws = (char*)d_ws;
  size_t off = 0;
  auto alloc = [&](size_t bytes) -> void* {
    void* p = ws + off;
    off += (bytes + 255) & ~(size_t)255;
    return p;
  };
  short* xb     = (short*)alloc((size_t)S_LEN * DIM * 2);
  short* wqkvT  = (short*)alloc((size_t)QS * DIM * 2);     // [6144][4096]
  short* woT    = (short*)alloc((size_t)DIM * DIM * 2);
  short* qkv    = (short*)alloc((size_t)S_LEN * QS * 2);   // [2048][6144]
  short* vtg    = (short*)alloc((size_t)KVD * S_LEN * 2);  // [1024][2048]
  short* ao     = (short*)alloc((size_t)S_LEN * DIM * 2);
  float* ct     = (float*)alloc((size_t)S_LEN * 64 * 4);
  float* st     = (float*)alloc((size_t)S_LEN * 64 * 4);

  rope_tables_k<<<(S_LEN * 64) / 256, 256, 0, stream>>>(ct, st);
  cast_f32_bf16_k<<<(S_LEN * DIM / 4) / 256, 256, 0, stream>>>(x, xb, S_LEN * DIM / 4);
  transpose_cast_k<<<dim3(DIM / 32, DIM / 32), dim3(32, 8), 0, stream>>>(wq, wqkvT, DIM, DIM);
  transpose_cast_k<<<dim3(KVD / 32, DIM / 32), dim3(32, 8), 0, stream>>>(
      wk, wqkvT + (size_t)4096 * DIM, DIM, KVD);
  transpose_cast_k<<<dim3(KVD / 32, DIM / 32), dim3(32, 8), 0, stream>>>(
      wv, wqkvT + (size_t)5120 * DIM, DIM, KVD);
  transpose_cast_k<<<dim3(DIM / 32, DIM / 32), dim3(32, 8), 0, stream>>>(wo, woT, DIM, DIM);

  // fused QKV projection: [2048][6144], 8-phase 256x256 tiles, 192 blocks
  gemm8p_k<<<dim3((S_LEN / 256) * (QS / 256)), 512, 0, stream>>>(
      xb, wqkvT, qkv, S_LEN, QS, DIM);

  rope_apply_k<<<(S_LEN * NH * 64) / 256, 256, 0, stream>>>(qkv, QS, ct, st, NH);
  rope_apply_k<<<(S_LEN * NKV * 64) / 256, 256, 0, stream>>>(qkv + 4096, QS, ct, st, NKV);

  transpose_bf16_k<<<dim3(KVD / 32, S_LEN / 32), dim3(32, 8), 0, stream>>>(
      qkv + 5120, vtg, S_LEN, KVD, QS);

  attn_k<<<dim3(512), 256, 0, stream>>>(qkv, qkv + 4096, vtg, ao);

  // output projection: 128x256 tiles -> 256 blocks (full machine), depth-3 pipeline
  gemm_p<128, 3, 0><<<dim3((S_LEN / 128) * (DIM / 256)), 512, 0, stream>>>(
      ao, woT, out, S_LEN, DIM, DIM);
}

// Round 9
// 354.085 us; speedup vs baseline: 1.6338x; 1.0275x over previous
//
#include <hip/hip_runtime.h>
#include <hip/hip_bf16.h>
#include <cstdint>
#include <cmath>

#define DIM 4096
#define NH 32
#define NKV 8
#define HD 128
#define S_LEN 2048
#define KVD (NKV * HD)   // 1024
#define QS 6144          // fused qkv row stride
#define SCALE 0.08838834764831845f

typedef __attribute__((ext_vector_type(4))) float f32x4;
typedef __attribute__((ext_vector_type(8))) short short8;

__device__ __forceinline__ short f2bf(float f) {
  union { float f; uint32_t u; } v; v.f = f;
  uint32_t u = v.u;
  u += 0x7fffu + ((u >> 16) & 1u);
  return (short)(u >> 16);
}
__device__ __forceinline__ float bf2f(short b) {
  union { uint32_t u; float f; } v; v.u = ((uint32_t)(uint16_t)b) << 16;
  return v.f;
}

__device__ __forceinline__ void async16(const void* g, void* l) {
  __builtin_amdgcn_global_load_lds(
      (__attribute__((address_space(1))) void*)(g),
      (__attribute__((address_space(3))) void*)(l), 16, 0, 0);
}

// ---------------- small prep kernels ----------------

__global__ void rope_tables_k(float* __restrict__ ct, float* __restrict__ st) {
  const int i = blockIdx.x * blockDim.x + threadIdx.x;
  if (i >= S_LEN * 64) return;
  const int s = i >> 6, d = i & 63;
  const float inv = powf(10000.0f, -(float)(2 * d) / 128.0f);
  const float fr = (float)s * inv;
  ct[i] = cosf(fr);
  st[i] = sinf(fr);
}

__global__ void cast_f32_bf16_k(const float* __restrict__ in, short* __restrict__ out, int n4) {
  const int i = blockIdx.x * blockDim.x + threadIdx.x;
  if (i >= n4) return;
  const float4 v = ((const float4*)in)[i];
  short4 o;
  o.x = f2bf(v.x); o.y = f2bf(v.y); o.z = f2bf(v.z); o.w = f2bf(v.w);
  ((short4*)out)[i] = o;
}

// w: [K][N] f32 row-major  ->  wt: [N][K] bf16 row-major
__global__ void transpose_cast_k(const float* __restrict__ wsrc, short* __restrict__ wt,
                                 int K, int N) {
  __shared__ float tile[32][33];
  const int tx = threadIdx.x, ty = threadIdx.y;
  const int c0 = blockIdx.x * 32, r0 = blockIdx.y * 32;
#pragma unroll
  for (int j = 0; j < 4; ++j)
    tile[ty + j * 8][tx] = wsrc[(size_t)(r0 + ty + j * 8) * N + c0 + tx];
  __syncthreads();
#pragma unroll
  for (int j = 0; j < 4; ++j)
    wt[(size_t)(c0 + ty + j * 8) * K + r0 + tx] = f2bf(tile[tx][ty + j * 8]);
}

// bf16 transpose: in [R][C] (row stride ldi) -> out [C][R]
__global__ void transpose_bf16_k(const short* __restrict__ in, short* __restrict__ out,
                                 int R, int C, int ldi) {
  __shared__ short tile[32][33];
  const int tx = threadIdx.x, ty = threadIdx.y;
  const int c0 = blockIdx.x * 32, r0 = blockIdx.y * 32;
#pragma unroll
  for (int j = 0; j < 4; ++j)
    tile[ty + j * 8][tx] = in[(size_t)(r0 + ty + j * 8) * ldi + c0 + tx];
  __syncthreads();
#pragma unroll
  for (int j = 0; j < 4; ++j)
    out[(size_t)(c0 + ty + j * 8) * R + r0 + tx] = tile[tx][ty + j * 8];
}

// in-place RoPE on bf16 [S][*] with row stride ld; thread handles (d, d+64) pair.
// nheads=40 covers fused q (cols 0..4095) AND k (cols 4096..5119) in one pass.
__global__ void rope_apply_k(short* __restrict__ xq, int ld, const float* __restrict__ ct,
                             const float* __restrict__ st, int nheads) {
  const int i = blockIdx.x * blockDim.x + threadIdx.x;
  const int total = S_LEN * nheads * 64;
  if (i >= total) return;
  const int d = i & 63;
  const int t = i >> 6;
  const int hh = t % nheads;
  const int s = t / nheads;
  short* p = xq + (size_t)s * ld + hh * HD + d;
  const float x1 = bf2f(p[0]);
  const float x2 = bf2f(p[64]);
  const float c = ct[(s << 6) + d];
  const float sn = st[(s << 6) + d];
  p[0]  = f2bf(x1 * c - x2 * sn);
  p[64] = f2bf(x2 * c + x1 * sn);
}

// ---------------- 256x192 3-phase GEMM for QKV (bf16 out), grid = 8x32 = 256 ----------
// 8 waves (4M x 2N), per-wave C = 64x96 (acc[4][6]). BK=64, dbuf LDS 112KB, XOR swizzle.
// Buffer lifetime (buf[t&1] holds tile t): B0(t),A(t) ds_read at p2(t-1);
// B1(t),B2(t) ds_read at p0(t). => after p0(t)'s END barrier buf[t&1] has NO
// future readers, so stage(t+2) (same buffer) issues at p1(t).  [R8's bug: it
// issued at p0(t), clobbering B1/B2 before their reads.]
// vmcnt ledger: stage(t+2)@p1(t) -> queue at p1(t) = t+1's 7 + t+2's 7 = 14;
// vmcnt(7) there retires exactly tile t+1 (3-phase flight), before p2(t)'s reads
// of t+1 (cross-wave safe via p1's END barrier). p0/p2 vmcnt(7) are pass-through.
// Tail: p1(KT-2) has no stage -> vmcnt(0) drains tile KT-1 (the R6 lesson);
// tile KT-1 all-resident.

#define PH3_SYNC(VM)                                             \
  asm volatile("s_waitcnt vmcnt(" #VM ")" ::: "memory");         \
  __builtin_amdgcn_s_barrier();                                  \
  asm volatile("s_waitcnt lgkmcnt(0)" ::: "memory");             \
  __builtin_amdgcn_sched_barrier(0);                             \
  __builtin_amdgcn_s_setprio(1)

#define PH3_END()                                                \
  __builtin_amdgcn_s_setprio(0);                                 \
  __builtin_amdgcn_sched_barrier(0);                             \
  __builtin_amdgcn_s_barrier()

__global__ __launch_bounds__(512, 2) void gemm192_k(
    const short* __restrict__ A, const short* __restrict__ BT,
    short* __restrict__ C, int M, int N, int K) {
  __shared__ __attribute__((aligned(16))) short ldsA[2][256 * 64];
  __shared__ __attribute__((aligned(16))) short ldsB[2][192 * 64];
  const int tid = threadIdx.x;
  const int l = tid & 63, w = tid >> 6;
  const int wrM = w >> 1, wcN = w & 1;     // 4M x 2N waves
  const int lrow = l & 15, lg = l >> 4;
  const int cofs[2] = {(lg ^ (lrow & 7)) << 3, ((4 + lg) ^ (lrow & 7)) << 3};
  (void)M;

  int bid = blockIdx.x;
  const int cpx = gridDim.x >> 3;          // XCD-chunked bijective (grid % 8 == 0)
  bid = (bid & 7) * cpx + (bid >> 3);
  const int ntn = N / 192;                 // 32
  const int m0 = (bid / ntn) << 8;
  const int n0 = (bid % ntn) * 192;

  // stage ALL of tile tau: B 192x64 (3 loads) + A 256x64 (4 loads) = 7/thread
  auto stage = [&](int tau) {
    const int k0 = tau << 6;
    short* bd = &ldsB[tau & 1][0];
    short* ad = &ldsA[tau & 1][0];
#pragma unroll
    for (int it = 0; it < 3; ++it) {
      const int e = it * 512 + tid;
      const int row = e >> 3;
      const int js = (e & 7) ^ (row & 7);
      async16(BT + (size_t)(n0 + row) * K + k0 + js * 8, bd + e * 8);
    }
#pragma unroll
    for (int it = 0; it < 4; ++it) {
      const int e = it * 512 + tid;
      const int row = e >> 3;
      const int js = (e & 7) ^ (row & 7);
      async16(A + (size_t)(m0 + row) * K + k0 + js * 8, ad + e * 8);
    }
  };
  auto rdA = [&](short8 (&dst)[4][2], int b) {
    const short* p = &ldsA[b][0];
#pragma unroll
    for (int mi = 0; mi < 4; ++mi) {
      const int row = wrM * 64 + mi * 16 + lrow;
#pragma unroll
      for (int kk = 0; kk < 2; ++kk)
        dst[mi][kk] = *(const short8*)(p + row * 64 + cofs[kk]);
    }
  };
  auto rdB = [&](short8 (&dst)[2][2], int b, int pr) {
    const short* p = &ldsB[b][0];
#pragma unroll
    for (int ni = 0; ni < 2; ++ni) {
      const int row = wcN * 96 + pr * 32 + ni * 16 + lrow;
#pragma unroll
      for (int kk = 0; kk < 2; ++kk)
        dst[ni][kk] = *(const short8*)(p + row * 64 + cofs[kk]);
    }
  };

  f32x4 acc[4][6] = {};
  auto third = [&](short8 (&Af)[4][2], int pr, short8 (&Bf)[2][2]) {
#pragma unroll
    for (int kk = 0; kk < 2; ++kk)
#pragma unroll
      for (int mi = 0; mi < 4; ++mi)
#pragma unroll
        for (int ni = 0; ni < 2; ++ni)
          acc[mi][pr * 2 + ni] = __builtin_amdgcn_mfma_f32_16x16x32_bf16(
              Af[mi][kk], Bf[ni][kk], acc[mi][pr * 2 + ni], 0, 0, 0);
  };

  short8 Aa[4][2], Ab[4][2], B0f[2][2], B1f[2][2], B2f[2][2];

  // prologue: stage t0, t1 (7+7); retire t0; pre-read B0(0), A(0)
  stage(0); stage(1);
  asm volatile("s_waitcnt vmcnt(7)" ::: "memory");
  __builtin_amdgcn_s_barrier();
  rdB(B0f, 0, 0);
  rdA(Aa, 0);

  const int KT = K >> 6;  // 64 (even)
  for (int u = 0; u < (KT - 2) / 2; ++u) {
    const int e = 2 * u;
    // ---- tile e (buf0, A=Aa) ----
    rdB(B1f, 0, 1); rdB(B2f, 0, 2);          // last reads of buf0's B region
    PH3_SYNC(7);  third(Aa, 0, B0f); PH3_END();
    stage(e + 2);                            // buf0 now dead -> safe to overwrite
    PH3_SYNC(7);  third(Aa, 1, B1f); PH3_END();   // retires tile e+1
    rdB(B0f, 1, 0); rdA(Ab, 1);              // tile e+1 (retired, barrier-safe)
    PH3_SYNC(7);  third(Aa, 2, B2f); PH3_END();
    // ---- tile e+1 (buf1, A=Ab) ----
    rdB(B1f, 1, 1); rdB(B2f, 1, 2);
    PH3_SYNC(7);  third(Ab, 0, B0f); PH3_END();
    stage(e + 3);
    PH3_SYNC(7);  third(Ab, 1, B1f); PH3_END();   // retires tile e+2
    rdB(B0f, 0, 0); rdA(Aa, 0);
    PH3_SYNC(7);  third(Ab, 2, B2f); PH3_END();
  }
  // ---- tail tile KT-2 (buf0, A=Aa): no staging ----
  rdB(B1f, 0, 1); rdB(B2f, 0, 2);
  PH3_SYNC(7);  third(Aa, 0, B0f); PH3_END();    // queue = KT-1's 7 -> pass
  PH3_SYNC(0);  third(Aa, 1, B1f); PH3_END();    // drains tile KT-1
  rdB(B0f, 1, 0); rdA(Ab, 1);
  PH3_SYNC(0);  third(Aa, 2, B2f); PH3_END();
  // ---- tile KT-1 (buf1, A=Ab): all data resident ----
  rdB(B1f, 1, 1); rdB(B2f, 1, 2);
  PH3_SYNC(0);  third(Ab, 0, B0f); PH3_END();
  PH3_SYNC(0);  third(Ab, 1, B1f); PH3_END();
  PH3_SYNC(0);  third(Ab, 2, B2f); PH3_END();

  // epilogue
  const int orow0 = m0 + wrM * 64 + lg * 4;
  const int ocol0 = n0 + wcN * 96 + lrow;
#pragma unroll
  for (int mi = 0; mi < 4; ++mi)
#pragma unroll
    for (int n = 0; n < 6; ++n)
#pragma unroll
      for (int r = 0; r < 4; ++r)
        C[(size_t)(orow0 + mi * 16 + r) * N + (ocol0 + n * 16)] = f2bf(acc[mi][n][r]);
}

// ---------------- pipelined GEMM (WO: BM=128, NBUF=3, fp32 out) ----------------

template <int BM, int NBUF, int OUT_BF16>
__global__ __launch_bounds__(512, 2) void gemm_p(
    const short* __restrict__ A, const short* __restrict__ BT,
    void* __restrict__ Cv, int M, int N, int K) {
  constexpr int TILE = (BM + 256) * 64;
  constexpr int LA = BM / 64;
  constexpr int NP = BM / 64;
  __shared__ __attribute__((aligned(16))) short lds[NBUF][TILE];

  const int tid = threadIdx.x;
  const int w = tid >> 6, l = tid & 63;
  const int wr = w >> 2, wc = w & 3;
  const int lrow = l & 15, lg = l >> 4;

  int bid = blockIdx.x;
  const int cpx = gridDim.x >> 3;
  bid = (bid & 7) * cpx + (bid >> 3);
  const int ntn = N >> 8;
  const int m0 = (bid / ntn) * BM;
  const int n0 = (bid % ntn) << 8;

  auto stage = [&](int kt, int buf) {
    const int k0 = kt << 6;
    short* dst = &lds[buf][0];
#pragma unroll
    for (int it = 0; it < LA; ++it) {
      const int e = it * 512 + tid;
      const int row = e >> 3, j = e & 7;
      const int jsrc = j ^ (row & 7);
      async16(A + (size_t)(m0 + row) * K + k0 + jsrc * 8, dst + e * 8);
    }
#pragma unroll
    for (int it = 0; it < 4; ++it) {
      const int e = it * 512 + tid;
      const int row = e >> 3, j = e & 7;
      const int jsrc = j ^ (row & 7);
      async16(BT + (size_t)(n0 + row) * K + k0 + jsrc * 8, dst + BM * 64 + e * 8);
    }
  };

  auto vwait = [&](int J) {
    if constexpr (BM == 256) {
      if (J >= 1) asm volatile("s_waitcnt vmcnt(8)" ::: "memory");
      else        asm volatile("s_waitcnt vmcnt(0)" ::: "memory");
    } else {
      if (J >= 2)      asm volatile("s_waitcnt vmcnt(12)" ::: "memory");
      else if (J == 1) asm volatile("s_waitcnt vmcnt(6)" ::: "memory");
      else             asm volatile("s_waitcnt vmcnt(0)" ::: "memory");
    }
  };

  f32x4 acc[NP * 2][4] = {};

  const int KT = K >> 6;
#pragma unroll
  for (int t = 0; t < NBUF; ++t) stage(t, t);
  vwait(NBUF - 1);
  __builtin_amdgcn_s_barrier();

  for (int kt = 0; kt < KT; ++kt) {
    const int buf = kt % NBUF;
    const short* Ah = &lds[buf][0];
    const short* Bh = &lds[buf][BM * 64];
    short8 bfrag[2][4];

#pragma unroll
    for (int p = 0; p < NP; ++p) {
      short8 afrag[2][2];
#pragma unroll
      for (int mi = 0; mi < 2; ++mi) {
        const int row = wr * (BM / 2) + (p * 2 + mi) * 16 + lrow;
#pragma unroll
        for (int kk = 0; kk < 2; ++kk)
          afrag[mi][kk] =
              *(const short8*)(Ah + row * 64 + (((kk * 4 + lg) ^ (row & 7)) << 3));
      }
      if (p == 0) {
#pragma unroll
        for (int n = 0; n < 4; ++n) {
          const int row = wc * 64 + n * 16 + lrow;
#pragma unroll
          for (int kk = 0; kk < 2; ++kk)
            bfrag[kk][n] =
                *(const short8*)(Bh + row * 64 + (((kk * 4 + lg) ^ (row & 7)) << 3));
        }
      }
      __builtin_amdgcn_s_barrier();
      asm volatile("s_waitcnt lgkmcnt(0)" ::: "memory");
      __builtin_amdgcn_s_setprio(1);
#pragma unroll
      for (int kk = 0; kk < 2; ++kk)
#pragma unroll
        for (int mi = 0; mi < 2; ++mi)
#pragma unroll
          for (int n = 0; n < 4; ++n)
            acc[p * 2 + mi][n] = __builtin_amdgcn_mfma_f32_16x16x32_bf16(
                afrag[mi][kk], bfrag[kk][n], acc[p * 2 + mi][n], 0, 0, 0);
      __builtin_amdgcn_s_setprio(0);
      __builtin_amdgcn_s_barrier();
    }
    if (kt + 1 < KT) {
      const int nst = kt + NBUF;
      if (nst < KT) stage(nst, buf);
      const int J = (nst < KT ? nst : KT - 1) - (kt + 1);
      vwait(J);
      __builtin_amdgcn_s_barrier();
    }
  }

  const int orow0 = m0 + wr * (BM / 2) + lg * 4;
  const int ocol0 = n0 + wc * 64 + lrow;
#pragma unroll
  for (int m = 0; m < NP * 2; ++m)
#pragma unroll
    for (int n = 0; n < 4; ++n)
#pragma unroll
      for (int r = 0; r < 4; ++r) {
        const size_t idx = (size_t)(orow0 + m * 16 + r) * N + (ocol0 + n * 16);
        if (OUT_BF16)
          ((short*)Cv)[idx] = f2bf(acc[m][n][r]);
        else
          ((float*)Cv)[idx] = acc[m][n][r];
      }
}

// ---------------- flash attention (causal, GQA 4:1) ----------------

__global__ __launch_bounds__(256, 3) void attn_k(
    const short* __restrict__ Q, const short* __restrict__ Kc,
    const short* __restrict__ VTg, short* __restrict__ O) {
  __shared__ __attribute__((aligned(16))) short Ks[2][64 * 128];
  __shared__ __attribute__((aligned(16))) short Vt[2][128 * 64];
  __shared__ __attribute__((aligned(16))) short Ps[4][32 * 64];

  const int tid = threadIdx.x;
  const int w = tid >> 6, l = tid & 63;
  const int lrow = l & 15, lg = l >> 4;

  int b = blockIdx.x, h, qt;
  if (b < 256) { h = b >> 3; qt = 15 - (b & 7); }
  else { b -= 256; h = b >> 3; qt = b & 7; }
  const int kvh = h >> 2;
  const int qb0 = qt * 128;
  const int qrow0 = qb0 + w * 32;
  const int nkt = 2 * qt + 2;

  short8 qf[2][4];
#pragma unroll
  for (int nq = 0; nq < 2; ++nq) {
    const short* qp = Q + (size_t)(qrow0 + nq * 16 + lrow) * QS + h * HD;
#pragma unroll
    for (int c = 0; c < 4; ++c) qf[nq][c] = *(const short8*)(qp + c * 32 + lg * 8);
  }

  f32x4 o_acc[2][8] = {};
  float m[2] = {-INFINITY, -INFINITY};
  float lsum[2] = {0.f, 0.f};

  auto stage = [&](int kb, int buf) {
    short* kd = Ks[buf];
    short* vd = Vt[buf];
#pragma unroll
    for (int it = 0; it < 4; ++it) {
      const int e = it * 256 + tid;
      const int row = e >> 4, j = e & 15;
      const int jsrc = (j & 8) | ((j ^ row) & 7);
      async16(Kc + (size_t)(kb + row) * QS + kvh * HD + jsrc * 8, kd + e * 8);
    }
#pragma unroll
    for (int it = 0; it < 4; ++it) {
      const int e = it * 256 + tid;
      const int d = e >> 3, j = e & 7;
      const int jsrc = (j ^ d) & 7;
      async16(VTg + (size_t)(kvh * HD + d) * S_LEN + kb + jsrc * 8, vd + e * 8);
    }
  };

  stage(0, 0);
  int cur = 0;

  for (int kt = 0; kt < nkt; ++kt) {
    __syncthreads();
    if (kt + 1 < nkt) stage((kt + 1) * 64, cur ^ 1);
    const int kb = kt * 64;

    if (kb <= qrow0 + 31) {
      const char* ks = (const char*)Ks[cur];
      const char* vt = (const char*)Vt[cur];
      char* psb = (char*)Ps[w];

      f32x4 stq[4][2] = {};
#pragma unroll
      for (int c = 0; c < 4; ++c) {
#pragma unroll
        for (int mk = 0; mk < 4; ++mk) {
          const short8 kf = *(const short8*)(
              ks + (mk * 16 + lrow) * 256 + (((c * 4 + lg) ^ (lrow & 7)) << 4));
          stq[mk][0] = __builtin_amdgcn_mfma_f32_16x16x32_bf16(kf, qf[0][c], stq[mk][0], 0, 0, 0);
          stq[mk][1] = __builtin_amdgcn_mfma_f32_16x16x32_bf16(kf, qf[1][c], stq[mk][1], 0, 0, 0);
        }
      }

      const bool needmask = (kb + 63 > qrow0);
#pragma unroll
      for (int mk = 0; mk < 4; ++mk)
#pragma unroll
        for (int nq = 0; nq < 2; ++nq)
#pragma unroll
          for (int r = 0; r < 4; ++r) {
            float v = stq[mk][nq][r] * SCALE;
            if (needmask && (kb + mk * 16 + lg * 4 + r > qrow0 + nq * 16 + lrow))
              v = -INFINITY;
            stq[mk][nq][r] = v;
          }

      float vmax[2];
#pragma unroll
      for (int nq = 0; nq < 2; ++nq) {
        float v = stq[0][nq][0];
#pragma unroll
        for (int mk = 0; mk < 4; ++mk)
#pragma unroll
          for (int r = 0; r < 4; ++r) v = fmaxf(v, stq[mk][nq][r]);
        v = fmaxf(v, __shfl_xor(v, 16));
        v = fmaxf(v, __shfl_xor(v, 32));
        vmax[nq] = v;
      }

      const int small = (vmax[0] <= m[0] + 8.0f) && (vmax[1] <= m[1] + 8.0f);
      if (!__all(small)) {
        float al[2];
#pragma unroll
        for (int nq = 0; nq < 2; ++nq) {
          const float mn = fmaxf(m[nq], vmax[nq]);
          al[nq] = __expf(m[nq] - mn);
          m[nq] = mn;
          lsum[nq] *= al[nq];
        }
#pragma unroll
        for (int mmq = 0; mmq < 2; ++mmq)
#pragma unroll
          for (int r = 0; r < 4; ++r) {
            const float a = __shfl(al[mmq], lg * 4 + r);
#pragma unroll
            for (int d = 0; d < 8; ++d) o_acc[mmq][d][r] *= a;
          }
      }

      float rs[2] = {0.f, 0.f};
#pragma unroll
      for (int nq = 0; nq < 2; ++nq) {
#pragma unroll
        for (int mk = 0; mk < 4; ++mk) {
          const float p0 = __expf(stq[mk][nq][0] - m[nq]);
          const float p1 = __expf(stq[mk][nq][1] - m[nq]);
          const float p2 = __expf(stq[mk][nq][2] - m[nq]);
          const float p3 = __expf(stq[mk][nq][3] - m[nq]);
          rs[nq] += (p0 + p1) + (p2 + p3);
          __hip_bfloat16 b0 = __float2bfloat16(p0), b1 = __float2bfloat16(p1);
          __hip_bfloat16 b2 = __float2bfloat16(p2), b3 = __float2bfloat16(p3);
          short4 pk;
          pk.x = *(short*)&b0; pk.y = *(short*)&b1; pk.z = *(short*)&b2; pk.w = *(short*)&b3;
          const int q = nq * 16 + lrow;
          *(short4*)(psb + q * 128 + ((mk * 32 + lg * 8) ^ ((q & 7) << 4))) = pk;
        }
        float r2 = rs[nq];
        r2 += __shfl_xor(r2, 16);
        r2 += __shfl_xor(r2, 32);
        lsum[nq] += r2;
      }

#pragma unroll
      for (int cc = 0; cc < 2; ++cc) {
        const int chunk = ((cc * 4 + lg) ^ (lrow & 7)) << 4;
        const short8 pa0 = *(const short8*)(psb + lrow * 128 + chunk);
        const short8 pa1 = *(const short8*)(psb + (16 + lrow) * 128 + chunk);
#pragma unroll
        for (int d = 0; d < 8; ++d) {
          const short8 vf = *(const short8*)(vt + (d * 16 + lrow) * 128 + chunk);
          o_acc[0][d] = __builtin_amdgcn_mfma_f32_16x16x32_bf16(pa0, vf, o_acc[0][d], 0, 0, 0);
          o_acc[1][d] = __builtin_amdgcn_mfma_f32_16x16x32_bf16(pa1, vf, o_acc[1][d], 0, 0, 0);
        }
      }
    }
    cur ^= 1;
  }

  float linv[2] = {1.0f / lsum[0], 1.0f / lsum[1]};
#pragma unroll
  for (int mmq = 0; mmq < 2; ++mmq)
#pragma unroll
    for (int r = 0; r < 4; ++r) {
      const float li = __shfl(linv[mmq], lg * 4 + r);
      short* op = O + (size_t)(qrow0 + mmq * 16 + lg * 4 + r) * DIM + h * HD;
#pragma unroll
      for (int d = 0; d < 8; ++d)
        op[d * 16 + lrow] = f2bf(o_acc[mmq][d][r] * li);
    }
}

// ---------------- launch ----------------

extern "C" void kernel_launch(void* const* d_in, const int* in_sizes, int n_in,
                              void* d_out, int out_size, void* d_ws, size_t ws_size,
                              hipStream_t stream) {
  const float* x  = (const float*)d_in[0];
  const float* wq = (const float*)d_in[1];
  const float* wk = (const float*)d_in[2];
  const float* wv = (const float*)d_in[3];
  const float* wo = (const float*)d_in[4];
  float* out = (float*)d_out;
  (void)in_sizes; (void)n_in; (void)out_size; (void)ws_size;

  char* ws = (char*)d_ws;
  size_t off = 0;
  auto alloc = [&](size_t bytes) -> void* {
    void* p = ws + off;
    off += (bytes + 255) & ~(size_t)255;
    return p;
  };
  short* xb     = (short*)alloc((size_t)S_LEN * DIM * 2);
  short* wqkvT  = (short*)alloc((size_t)QS * DIM * 2);     // [6144][4096]
  short* woT    = (short*)alloc((size_t)DIM * DIM * 2);
  short* qkv    = (short*)alloc((size_t)S_LEN * QS * 2);   // [2048][6144]
  short* vtg    = (short*)alloc((size_t)KVD * S_LEN * 2);  // [1024][2048]
  short* ao     = (short*)alloc((size_t)S_LEN * DIM * 2);
  float* ct     = (float*)alloc((size_t)S_LEN * 64 * 4);
  float* st     = (float*)alloc((size_t)S_LEN * 64 * 4);

  rope_tables_k<<<(S_LEN * 64) / 256, 256, 0, stream>>>(ct, st);
  cast_f32_bf16_k<<<(S_LEN * DIM / 4) / 256, 256, 0, stream>>>(x, xb, S_LEN * DIM / 4);
  transpose_cast_k<<<dim3(DIM / 32, DIM / 32), dim3(32, 8), 0, stream>>>(wq, wqkvT, DIM, DIM);
  transpose_cast_k<<<dim3(KVD / 32, DIM / 32), dim3(32, 8), 0, stream>>>(
      wk, wqkvT + (size_t)4096 * DIM, DIM, KVD);
  transpose_cast_k<<<dim3(KVD / 32, DIM / 32), dim3(32, 8), 0, stream>>>(
      wv, wqkvT + (size_t)5120 * DIM, DIM, KVD);
  transpose_cast_k<<<dim3(DIM / 32, DIM / 32), dim3(32, 8), 0, stream>>>(wo, woT, DIM, DIM);

  // fused QKV projection: [2048][6144], 256x192 tiles -> grid 256 (full machine)
  gemm192_k<<<dim3((S_LEN / 256) * (QS / 192)), 512, 0, stream>>>(
      xb, wqkvT, qkv, S_LEN, QS, DIM);

  // one RoPE pass over q+k heads (cols 0..5119 = 40 contiguous "heads")
  rope_apply_k<<<(S_LEN * 40 * 64) / 256, 256, 0, stream>>>(qkv, QS, ct, st, 40);

  transpose_bf16_k<<<dim3(KVD / 32, S_LEN / 32), dim3(32, 8), 0, stream>>>(
      qkv + 5120, vtg, S_LEN, KVD, QS);

  attn_k<<<dim3(512), 256, 0, stream>>>(qkv, qkv + 4096, vtg, ao);

  // output projection: 128x256 tiles -> 256 blocks (full machine), depth-3 pipeline
  gemm_p<128, 3, 0><<<dim3((S_LEN / 128) * (DIM / 256)), 512, 0, stream>>>(
      ao, woT, out, S_LEN, DIM, DIM);
}

// Round 10
// 343.578 us; speedup vs baseline: 1.6838x; 1.0306x over previous
//
#include <hip/hip_runtime.h>
#include <hip/hip_bf16.h>
#include <cstdint>
#include <cmath>

#define DIM 4096
#define NH 32
#define NKV 8
#define HD 128
#define S_LEN 2048
#define KVD (NKV * HD)   // 1024
#define QS 6144          // fused qkv row stride
#define SCALE 0.08838834764831845f

typedef __attribute__((ext_vector_type(4))) float f32x4;
typedef __attribute__((ext_vector_type(8))) short short8;

__device__ __forceinline__ short f2bf(float f) {
  union { float f; uint32_t u; } v; v.f = f;
  uint32_t u = v.u;
  u += 0x7fffu + ((u >> 16) & 1u);
  return (short)(u >> 16);
}
__device__ __forceinline__ float bf2f(short b) {
  union { uint32_t u; float f; } v; v.u = ((uint32_t)(uint16_t)b) << 16;
  return v.f;
}

__device__ __forceinline__ void async16(const void* g, void* l) {
  __builtin_amdgcn_global_load_lds(
      (__attribute__((address_space(1))) void*)(g),
      (__attribute__((address_space(3))) void*)(l), 16, 0, 0);
}

// ---------------- small prep kernels ----------------

__global__ void rope_tables_k(float* __restrict__ ct, float* __restrict__ st) {
  const int i = blockIdx.x * blockDim.x + threadIdx.x;
  if (i >= S_LEN * 64) return;
  const int s = i >> 6, d = i & 63;
  const float inv = powf(10000.0f, -(float)(2 * d) / 128.0f);
  const float fr = (float)s * inv;
  ct[i] = cosf(fr);
  st[i] = sinf(fr);
}

__global__ void cast_f32_bf16_k(const float* __restrict__ in, short* __restrict__ out, int n4) {
  const int i = blockIdx.x * blockDim.x + threadIdx.x;
  if (i >= n4) return;
  const float4 v = ((const float4*)in)[i];
  short4 o;
  o.x = f2bf(v.x); o.y = f2bf(v.y); o.z = f2bf(v.z); o.w = f2bf(v.w);
  ((short4*)out)[i] = o;
}

// w: [K][N] f32 row-major  ->  wt: [N][K] bf16 row-major
__global__ void transpose_cast_k(const float* __restrict__ wsrc, short* __restrict__ wt,
                                 int K, int N) {
  __shared__ float tile[32][33];
  const int tx = threadIdx.x, ty = threadIdx.y;
  const int c0 = blockIdx.x * 32, r0 = blockIdx.y * 32;
#pragma unroll
  for (int j = 0; j < 4; ++j)
    tile[ty + j * 8][tx] = wsrc[(size_t)(r0 + ty + j * 8) * N + c0 + tx];
  __syncthreads();
#pragma unroll
  for (int j = 0; j < 4; ++j)
    wt[(size_t)(c0 + ty + j * 8) * K + r0 + tx] = f2bf(tile[tx][ty + j * 8]);
}

// bf16 transpose: in [R][C] (row stride ldi) -> out [C][R]
__global__ void transpose_bf16_k(const short* __restrict__ in, short* __restrict__ out,
                                 int R, int C, int ldi) {
  __shared__ short tile[32][33];
  const int tx = threadIdx.x, ty = threadIdx.y;
  const int c0 = blockIdx.x * 32, r0 = blockIdx.y * 32;
#pragma unroll
  for (int j = 0; j < 4; ++j)
    tile[ty + j * 8][tx] = in[(size_t)(r0 + ty + j * 8) * ldi + c0 + tx];
  __syncthreads();
#pragma unroll
  for (int j = 0; j < 4; ++j)
    out[(size_t)(c0 + ty + j * 8) * R + r0 + tx] = tile[tx][ty + j * 8];
}

// in-place RoPE on bf16 [S][*] with row stride ld; thread handles (d, d+64) pair.
// nheads=40 covers fused q (cols 0..4095) AND k (cols 4096..5119) in one pass.
__global__ void rope_apply_k(short* __restrict__ xq, int ld, const float* __restrict__ ct,
                             const float* __restrict__ st, int nheads) {
  const int i = blockIdx.x * blockDim.x + threadIdx.x;
  const int total = S_LEN * nheads * 64;
  if (i >= total) return;
  const int d = i & 63;
  const int t = i >> 6;
  const int hh = t % nheads;
  const int s = t / nheads;
  short* p = xq + (size_t)s * ld + hh * HD + d;
  const float x1 = bf2f(p[0]);
  const float x2 = bf2f(p[64]);
  const float c = ct[(s << 6) + d];
  const float sn = st[(s << 6) + d];
  p[0]  = f2bf(x1 * c - x2 * sn);
  p[64] = f2bf(x2 * c + x1 * sn);
}

// SYNC with counted vmcnt AND counted lgkmcnt.
#define SYNC2(VM, LG)                                            \
  asm volatile("s_waitcnt vmcnt(" #VM ")" ::: "memory");         \
  __builtin_amdgcn_s_barrier();                                  \
  asm volatile("s_waitcnt lgkmcnt(" #LG ")" ::: "memory");       \
  __builtin_amdgcn_sched_barrier(0);                             \
  __builtin_amdgcn_s_setprio(1)

#define PH_END()                                                 \
  __builtin_amdgcn_s_setprio(0);                                 \
  __builtin_amdgcn_sched_barrier(0);                             \
  __builtin_amdgcn_s_barrier()

// ---------------- 256x192 3-phase GEMM for QKV (bf16 out), grid = 8x32 = 256 ----------
// 8 waves (4M x 2N), per-wave C = 64x96 (acc[4][6]). BK=64, dbuf LDS 112KB, XOR swizzle.
// Phase plan per tile t (buf c = t&1); all MFMA operands are read >=1 phase ahead,
// counted lgkm lets just-issued reads complete UNDER the MFMA burst:
//  p0: issue B1(t),B2(t) [8 rd]  | SYNC(vm7 pass, lg8)           | MFMA AxB0
//  p1: (no reads)                | SYNC(vm0: retires t+1's 7 staging loads, issued
//      3 phases ago; lg0: retires B1,B2 -> buf c has NO readers in flight)
//      stage(t+2) [7 gl, buf c]  -- write-after-read rigorous     | MFMA AxB1
//  p2: issue B0(t+1),A(t+1) [12 rd -- legal: t+1 staging drained at p1]
//                                | SYNC(vm7 pass, lg12)           | MFMA AxB2
// vm ledger: only outstanding group at p1(t) is stage(t+1) (issued p1(t-1) post-
// sync) -> vm0 there drains exactly 7 old loads. p0/p2 see 7 outstanding -> vm7
// pass-through. lg ledger: DS retires in order; lg8/lg12 retire everything older
// than the just-issued reads (which fly under MFMA). Tail peeled (R6 lesson).

__global__ __launch_bounds__(512, 2) void gemm192_k(
    const short* __restrict__ A, const short* __restrict__ BT,
    short* __restrict__ C, int M, int N, int K) {
  __shared__ __attribute__((aligned(16))) short ldsA[2][256 * 64];
  __shared__ __attribute__((aligned(16))) short ldsB[2][192 * 64];
  const int tid = threadIdx.x;
  const int l = tid & 63, w = tid >> 6;
  const int wrM = w >> 1, wcN = w & 1;     // 4M x 2N waves
  const int lrow = l & 15, lg = l >> 4;
  const int cofs[2] = {(lg ^ (lrow & 7)) << 3, ((4 + lg) ^ (lrow & 7)) << 3};
  (void)M;

  int bid = blockIdx.x;
  const int cpx = gridDim.x >> 3;          // XCD-chunked bijective (grid % 8 == 0)
  bid = (bid & 7) * cpx + (bid >> 3);
  const int ntn = N / 192;                 // 32
  const int m0 = (bid / ntn) << 8;
  const int n0 = (bid % ntn) * 192;

  auto stage = [&](int tau) {
    const int k0 = tau << 6;
    short* bd = &ldsB[tau & 1][0];
    short* ad = &ldsA[tau & 1][0];
#pragma unroll
    for (int it = 0; it < 3; ++it) {
      const int e = it * 512 + tid;
      const int row = e >> 3;
      const int js = (e & 7) ^ (row & 7);
      async16(BT + (size_t)(n0 + row) * K + k0 + js * 8, bd + e * 8);
    }
#pragma unroll
    for (int it = 0; it < 4; ++it) {
      const int e = it * 512 + tid;
      const int row = e >> 3;
      const int js = (e & 7) ^ (row & 7);
      async16(A + (size_t)(m0 + row) * K + k0 + js * 8, ad + e * 8);
    }
  };
  auto rdA = [&](short8 (&dst)[4][2], int b) {
    const short* p = &ldsA[b][0];
#pragma unroll
    for (int mi = 0; mi < 4; ++mi) {
      const int row = wrM * 64 + mi * 16 + lrow;
#pragma unroll
      for (int kk = 0; kk < 2; ++kk)
        dst[mi][kk] = *(const short8*)(p + row * 64 + cofs[kk]);
    }
  };
  auto rdB = [&](short8 (&dst)[2][2], int b, int pr) {
    const short* p = &ldsB[b][0];
#pragma unroll
    for (int ni = 0; ni < 2; ++ni) {
      const int row = wcN * 96 + pr * 32 + ni * 16 + lrow;
#pragma unroll
      for (int kk = 0; kk < 2; ++kk)
        dst[ni][kk] = *(const short8*)(p + row * 64 + cofs[kk]);
    }
  };

  f32x4 acc[4][6] = {};
  auto third = [&](short8 (&Af)[4][2], int pr, short8 (&Bf)[2][2]) {
#pragma unroll
    for (int kk = 0; kk < 2; ++kk)
#pragma unroll
      for (int mi = 0; mi < 4; ++mi)
#pragma unroll
        for (int ni = 0; ni < 2; ++ni)
          acc[mi][pr * 2 + ni] = __builtin_amdgcn_mfma_f32_16x16x32_bf16(
              Af[mi][kk], Bf[ni][kk], acc[mi][pr * 2 + ni], 0, 0, 0);
  };

  short8 Aa[4][2], Ab[4][2], B0f[2][2], B1f[2][2], B2f[2][2];

  // prologue: stage t0, t1; retire t0 (vm7); pre-read B0(0), A(0)
  stage(0); stage(1);
  asm volatile("s_waitcnt vmcnt(7)" ::: "memory");
  __builtin_amdgcn_s_barrier();
  rdB(B0f, 0, 0);
  rdA(Aa, 0);

  const int KT = K >> 6;  // 64 (even, >= 4)
  for (int u = 0; u < (KT - 2) / 2; ++u) {
    const int e = 2 * u;
    // ---- tile e (buf0, A=Aa) ----
    rdB(B1f, 0, 1); rdB(B2f, 0, 2);
    SYNC2(7, 8);  third(Aa, 0, B0f); PH_END();
    SYNC2(0, 0);  stage(e + 2); third(Aa, 1, B1f); PH_END();
    rdB(B0f, 1, 0); rdA(Ab, 1);
    SYNC2(7, 12); third(Aa, 2, B2f); PH_END();
    // ---- tile e+1 (buf1, A=Ab) ----
    rdB(B1f, 1, 1); rdB(B2f, 1, 2);
    SYNC2(7, 8);  third(Ab, 0, B0f); PH_END();
    SYNC2(0, 0);  stage(e + 3); third(Ab, 1, B1f); PH_END();
    rdB(B0f, 0, 0); rdA(Aa, 0);
    SYNC2(7, 12); third(Ab, 2, B2f); PH_END();
  }
  // ---- tail tile KT-2 (buf0, A=Aa): no staging ----
  rdB(B1f, 0, 1); rdB(B2f, 0, 2);
  SYNC2(7, 8);  third(Aa, 0, B0f); PH_END();     // outstanding: KT-1's 7 -> pass
  SYNC2(0, 0);  third(Aa, 1, B1f); PH_END();     // drains KT-1
  rdB(B0f, 1, 0); rdA(Ab, 1);
  SYNC2(0, 12); third(Aa, 2, B2f); PH_END();
  // ---- tile KT-1 (buf1, A=Ab): all staged data resident ----
  rdB(B1f, 1, 1); rdB(B2f, 1, 2);
  SYNC2(0, 8);  third(Ab, 0, B0f); PH_END();
  SYNC2(0, 0);  third(Ab, 1, B1f); PH_END();
  SYNC2(0, 0);  third(Ab, 2, B2f); PH_END();

  // epilogue
  const int orow0 = m0 + wrM * 64 + lg * 4;
  const int ocol0 = n0 + wcN * 96 + lrow;
#pragma unroll
  for (int mi = 0; mi < 4; ++mi)
#pragma unroll
    for (int n = 0; n < 6; ++n)
#pragma unroll
      for (int r = 0; r < 4; ++r)
        C[(size_t)(orow0 + mi * 16 + r) * N + (ocol0 + n * 16)] = f2bf(acc[mi][n][r]);
}

// ---------------- 128x256 2-phase GEMM for WO (fp32 out), grid = 16x16 = 256 ---------
// 8 waves (2M x 4N), per-wave C = 64x64 (acc[4][4]). BK=64, dbuf LDS 96KB, XOR swizzle.
// Same counted-vm/lg discipline as gemm192, 2 phases:
//  p0: issue Bh1(t) [4 rd]        | SYNC(vm6 pass, lg4)  | MFMA A x Bh0
//  p1: SYNC(vm0: retires t+1's 6, issued p1(t-1) post-sync; lg0: retires Bh1 ->
//      buf c reader-free) stage(t+2) + issue A(t+1),Bh0(t+1) [12 rd, legal]
//                                                          | MFMA A x Bh1
// lg ledger: p0's lg4 retires the 12 (A,Bh0) issued at p1(t-1), leaving Bh1 in
// flight under MFMA. Tail peeled.

__global__ __launch_bounds__(512, 2) void gemm_wo2_k(
    const short* __restrict__ A, const short* __restrict__ BT,
    float* __restrict__ C, int M, int N, int K) {
  __shared__ __attribute__((aligned(16))) short ldsA[2][128 * 64];
  __shared__ __attribute__((aligned(16))) short ldsB[2][256 * 64];
  const int tid = threadIdx.x;
  const int l = tid & 63, w = tid >> 6;
  const int wrM = w >> 2, wcN = w & 3;     // 2M x 4N waves
  const int lrow = l & 15, lg = l >> 4;
  const int cofs[2] = {(lg ^ (lrow & 7)) << 3, ((4 + lg) ^ (lrow & 7)) << 3};
  (void)M;

  int bid = blockIdx.x;
  const int cpx = gridDim.x >> 3;
  bid = (bid & 7) * cpx + (bid >> 3);
  const int ntn = N >> 8;                  // 16
  const int m0 = (bid / ntn) << 7;
  const int n0 = (bid % ntn) << 8;

  auto stage = [&](int tau) {
    const int k0 = tau << 6;
    short* ad = &ldsA[tau & 1][0];
    short* bd = &ldsB[tau & 1][0];
#pragma unroll
    for (int it = 0; it < 2; ++it) {
      const int e = it * 512 + tid;
      const int row = e >> 3;
      const int js = (e & 7) ^ (row & 7);
      async16(A + (size_t)(m0 + row) * K + k0 + js * 8, ad + e * 8);
    }
#pragma unroll
    for (int it = 0; it < 4; ++it) {
      const int e = it * 512 + tid;
      const int row = e >> 3;
      const int js = (e & 7) ^ (row & 7);
      async16(BT + (size_t)(n0 + row) * K + k0 + js * 8, bd + e * 8);
    }
  };
  auto rdA = [&](short8 (&dst)[4][2], int b) {
    const short* p = &ldsA[b][0];
#pragma unroll
    for (int mi = 0; mi < 4; ++mi) {
      const int row = wrM * 64 + mi * 16 + lrow;
#pragma unroll
      for (int kk = 0; kk < 2; ++kk)
        dst[mi][kk] = *(const short8*)(p + row * 64 + cofs[kk]);
    }
  };
  auto rdB = [&](short8 (&dst)[2][2], int b, int h) {
    const short* p = &ldsB[b][0];
#pragma unroll
    for (int ni = 0; ni < 2; ++ni) {
      const int row = wcN * 64 + h * 32 + ni * 16 + lrow;
#pragma unroll
      for (int kk = 0; kk < 2; ++kk)
        dst[ni][kk] = *(const short8*)(p + row * 64 + cofs[kk]);
    }
  };

  f32x4 acc[4][4] = {};
  auto half = [&](short8 (&Af)[4][2], int h, short8 (&Bf)[2][2]) {
#pragma unroll
    for (int kk = 0; kk < 2; ++kk)
#pragma unroll
      for (int mi = 0; mi < 4; ++mi)
#pragma unroll
        for (int ni = 0; ni < 2; ++ni)
          acc[mi][h * 2 + ni] = __builtin_amdgcn_mfma_f32_16x16x32_bf16(
              Af[mi][kk], Bf[ni][kk], acc[mi][h * 2 + ni], 0, 0, 0);
  };

  short8 Aa[4][2], Ab[4][2], H0[2][2], H1[2][2];

  // prologue
  stage(0); stage(1);
  asm volatile("s_waitcnt vmcnt(6)" ::: "memory");
  __builtin_amdgcn_s_barrier();
  rdA(Aa, 0); rdB(H0, 0, 0);

  const int KT = K >> 6;  // 64 (even, >= 4)
  for (int u = 0; u < (KT - 2) / 2; ++u) {
    const int e = 2 * u;
    // ---- tile e (buf0, A=Aa) ----
    rdB(H1, 0, 1);
    SYNC2(6, 4);  half(Aa, 0, H0); PH_END();
    SYNC2(0, 0);  stage(e + 2); rdA(Ab, 1); rdB(H0, 1, 0);
                  half(Aa, 1, H1); PH_END();
    // ---- tile e+1 (buf1, A=Ab) ----
    rdB(H1, 1, 1);
    SYNC2(6, 4);  half(Ab, 0, H0); PH_END();
    SYNC2(0, 0);  stage(e + 3); rdA(Aa, 0); rdB(H0, 0, 0);
                  half(Ab, 1, H1); PH_END();
  }
  // ---- tail tile KT-2 (buf0, A=Aa): no staging ----
  rdB(H1, 0, 1);
  SYNC2(6, 4);  half(Aa, 0, H0); PH_END();
  SYNC2(0, 0);  rdA(Ab, 1); rdB(H0, 1, 0);       // vm0 retired KT-1 first
                half(Aa, 1, H1); PH_END();
  // ---- tile KT-1 (buf1, A=Ab) ----
  rdB(H1, 1, 1);
  SYNC2(0, 4);  half(Ab, 0, H0); PH_END();
  SYNC2(0, 0);  half(Ab, 1, H1); PH_END();

  // epilogue (fp32)
  const int orow0 = m0 + wrM * 64 + lg * 4;
  const int ocol0 = n0 + wcN * 64 + lrow;
#pragma unroll
  for (int mi = 0; mi < 4; ++mi)
#pragma unroll
    for (int n = 0; n < 4; ++n)
#pragma unroll
      for (int r = 0; r < 4; ++r)
        C[(size_t)(orow0 + mi * 16 + r) * N + (ocol0 + n * 16)] = acc[mi][n][r];
}

// ---------------- flash attention (causal, GQA 4:1) ----------------

__global__ __launch_bounds__(256, 3) void attn_k(
    const short* __restrict__ Q, const short* __restrict__ Kc,
    const short* __restrict__ VTg, short* __restrict__ O) {
  __shared__ __attribute__((aligned(16))) short Ks[2][64 * 128];
  __shared__ __attribute__((aligned(16))) short Vt[2][128 * 64];
  __shared__ __attribute__((aligned(16))) short Ps[4][32 * 64];

  const int tid = threadIdx.x;
  const int w = tid >> 6, l = tid & 63;
  const int lrow = l & 15, lg = l >> 4;

  int b = blockIdx.x, h, qt;
  if (b < 256) { h = b >> 3; qt = 15 - (b & 7); }
  else { b -= 256; h = b >> 3; qt = b & 7; }
  const int kvh = h >> 2;
  const int qb0 = qt * 128;
  const int qrow0 = qb0 + w * 32;
  const int nkt = 2 * qt + 2;

  short8 qf[2][4];
#pragma unroll
  for (int nq = 0; nq < 2; ++nq) {
    const short* qp = Q + (size_t)(qrow0 + nq * 16 + lrow) * QS + h * HD;
#pragma unroll
    for (int c = 0; c < 4; ++c) qf[nq][c] = *(const short8*)(qp + c * 32 + lg * 8);
  }

  f32x4 o_acc[2][8] = {};
  float m[2] = {-INFINITY, -INFINITY};
  float lsum[2] = {0.f, 0.f};

  auto stage = [&](int kb, int buf) {
    short* kd = Ks[buf];
    short* vd = Vt[buf];
#pragma unroll
    for (int it = 0; it < 4; ++it) {
      const int e = it * 256 + tid;
      const int row = e >> 4, j = e & 15;
      const int jsrc = (j & 8) | ((j ^ row) & 7);
      async16(Kc + (size_t)(kb + row) * QS + kvh * HD + jsrc * 8, kd + e * 8);
    }
#pragma unroll
    for (int it = 0; it < 4; ++it) {
      const int e = it * 256 + tid;
      const int d = e >> 3, j = e & 7;
      const int jsrc = (j ^ d) & 7;
      async16(VTg + (size_t)(kvh * HD + d) * S_LEN + kb + jsrc * 8, vd + e * 8);
    }
  };

  stage(0, 0);
  int cur = 0;

  for (int kt = 0; kt < nkt; ++kt) {
    __syncthreads();
    if (kt + 1 < nkt) stage((kt + 1) * 64, cur ^ 1);
    const int kb = kt * 64;

    if (kb <= qrow0 + 31) {
      const char* ks = (const char*)Ks[cur];
      const char* vt = (const char*)Vt[cur];
      char* psb = (char*)Ps[w];

      f32x4 stq[4][2] = {};
#pragma unroll
      for (int c = 0; c < 4; ++c) {
#pragma unroll
        for (int mk = 0; mk < 4; ++mk) {
          const short8 kf = *(const short8*)(
              ks + (mk * 16 + lrow) * 256 + (((c * 4 + lg) ^ (lrow & 7)) << 4));
          stq[mk][0] = __builtin_amdgcn_mfma_f32_16x16x32_bf16(kf, qf[0][c], stq[mk][0], 0, 0, 0);
          stq[mk][1] = __builtin_amdgcn_mfma_f32_16x16x32_bf16(kf, qf[1][c], stq[mk][1], 0, 0, 0);
        }
      }

      const bool needmask = (kb + 63 > qrow0);
#pragma unroll
      for (int mk = 0; mk < 4; ++mk)
#pragma unroll
        for (int nq = 0; nq < 2; ++nq)
#pragma unroll
          for (int r = 0; r < 4; ++r) {
            float v = stq[mk][nq][r] * SCALE;
            if (needmask && (kb + mk * 16 + lg * 4 + r > qrow0 + nq * 16 + lrow))
              v = -INFINITY;
            stq[mk][nq][r] = v;
          }

      float vmax[2];
#pragma unroll
      for (int nq = 0; nq < 2; ++nq) {
        float v = stq[0][nq][0];
#pragma unroll
        for (int mk = 0; mk < 4; ++mk)
#pragma unroll
          for (int r = 0; r < 4; ++r) v = fmaxf(v, stq[mk][nq][r]);
        v = fmaxf(v, __shfl_xor(v, 16));
        v = fmaxf(v, __shfl_xor(v, 32));
        vmax[nq] = v;
      }

      const int small = (vmax[0] <= m[0] + 8.0f) && (vmax[1] <= m[1] + 8.0f);
      if (!__all(small)) {
        float al[2];
#pragma unroll
        for (int nq = 0; nq < 2; ++nq) {
          const float mn = fmaxf(m[nq], vmax[nq]);
          al[nq] = __expf(m[nq] - mn);
          m[nq] = mn;
          lsum[nq] *= al[nq];
        }
#pragma unroll
        for (int mmq = 0; mmq < 2; ++mmq)
#pragma unroll
          for (int r = 0; r < 4; ++r) {
            const float a = __shfl(al[mmq], lg * 4 + r);
#pragma unroll
            for (int d = 0; d < 8; ++d) o_acc[mmq][d][r] *= a;
          }
      }

      float rs[2] = {0.f, 0.f};
#pragma unroll
      for (int nq = 0; nq < 2; ++nq) {
#pragma unroll
        for (int mk = 0; mk < 4; ++mk) {
          const float p0 = __expf(stq[mk][nq][0] - m[nq]);
          const float p1 = __expf(stq[mk][nq][1] - m[nq]);
          const float p2 = __expf(stq[mk][nq][2] - m[nq]);
          const float p3 = __expf(stq[mk][nq][3] - m[nq]);
          rs[nq] += (p0 + p1) + (p2 + p3);
          __hip_bfloat16 b0 = __float2bfloat16(p0), b1 = __float2bfloat16(p1);
          __hip_bfloat16 b2 = __float2bfloat16(p2), b3 = __float2bfloat16(p3);
          short4 pk;
          pk.x = *(short*)&b0; pk.y = *(short*)&b1; pk.z = *(short*)&b2; pk.w = *(short*)&b3;
          const int q = nq * 16 + lrow;
          *(short4*)(psb + q * 128 + ((mk * 32 + lg * 8) ^ ((q & 7) << 4))) = pk;
        }
        float r2 = rs[nq];
        r2 += __shfl_xor(r2, 16);
        r2 += __shfl_xor(r2, 32);
        lsum[nq] += r2;
      }

#pragma unroll
      for (int cc = 0; cc < 2; ++cc) {
        const int chunk = ((cc * 4 + lg) ^ (lrow & 7)) << 4;
        const short8 pa0 = *(const short8*)(psb + lrow * 128 + chunk);
        const short8 pa1 = *(const short8*)(psb + (16 + lrow) * 128 + chunk);
#pragma unroll
        for (int d = 0; d < 8; ++d) {
          const short8 vf = *(const short8*)(vt + (d * 16 + lrow) * 128 + chunk);
          o_acc[0][d] = __builtin_amdgcn_mfma_f32_16x16x32_bf16(pa0, vf, o_acc[0][d], 0, 0, 0);
          o_acc[1][d] = __builtin_amdgcn_mfma_f32_16x16x32_bf16(pa1, vf, o_acc[1][d], 0, 0, 0);
        }
      }
    }
    cur ^= 1;
  }

  float linv[2] = {1.0f / lsum[0], 1.0f / lsum[1]};
#pragma unroll
  for (int mmq = 0; mmq < 2; ++mmq)
#pragma unroll
    for (int r = 0; r < 4; ++r) {
      const float li = __shfl(linv[mmq], lg * 4 + r);
      short* op = O + (size_t)(qrow0 + mmq * 16 + lg * 4 + r) * DIM + h * HD;
#pragma unroll
      for (int d = 0; d < 8; ++d)
        op[d * 16 + lrow] = f2bf(o_acc[mmq][d][r] * li);
    }
}

// ---------------- launch ----------------

extern "C" void kernel_launch(void* const* d_in, const int* in_sizes, int n_in,
                              void* d_out, int out_size, void* d_ws, size_t ws_size,
                              hipStream_t stream) {
  const float* x  = (const float*)d_in[0];
  const float* wq = (const float*)d_in[1];
  const float* wk = (const float*)d_in[2];
  const float* wv = (const float*)d_in[3];
  const float* wo = (const float*)d_in[4];
  float* out = (float*)d_out;
  (void)in_sizes; (void)n_in; (void)out_size; (void)ws_size;

  char* ws = (char*)d_ws;
  size_t off = 0;
  auto alloc = [&](size_t bytes) -> void* {
    void* p = ws + off;
    off += (bytes + 255) & ~(size_t)255;
    return p;
  };
  short* xb     = (short*)alloc((size_t)S_LEN * DIM * 2);
  short* wqkvT  = (short*)alloc((size_t)QS * DIM * 2);     // [6144][4096]
  short* woT    = (short*)alloc((size_t)DIM * DIM * 2);
  short* qkv    = (short*)alloc((size_t)S_LEN * QS * 2);   // [2048][6144]
  short* vtg    = (short*)alloc((size_t)KVD * S_LEN * 2);  // [1024][2048]
  short* ao     = (short*)alloc((size_t)S_LEN * DIM * 2);
  float* ct     = (float*)alloc((size_t)S_LEN * 64 * 4);
  float* st     = (float*)alloc((size_t)S_LEN * 64 * 4);

  rope_tables_k<<<(S_LEN * 64) / 256, 256, 0, stream>>>(ct, st);
  cast_f32_bf16_k<<<(S_LEN * DIM / 4) / 256, 256, 0, stream>>>(x, xb, S_LEN * DIM / 4);
  transpose_cast_k<<<dim3(DIM / 32, DIM / 32), dim3(32, 8), 0, stream>>>(wq, wqkvT, DIM, DIM);
  transpose_cast_k<<<dim3(KVD / 32, DIM / 32), dim3(32, 8), 0, stream>>>(
      wk, wqkvT + (size_t)4096 * DIM, DIM, KVD);
  transpose_cast_k<<<dim3(KVD / 32, DIM / 32), dim3(32, 8), 0, stream>>>(
      wv, wqkvT + (size_t)5120 * DIM, DIM, KVD);
  transpose_cast_k<<<dim3(DIM / 32, DIM / 32), dim3(32, 8), 0, stream>>>(wo, woT, DIM, DIM);

  // fused QKV projection: [2048][6144], 256x192 tiles -> grid 256 (full machine)
  gemm192_k<<<dim3((S_LEN / 256) * (QS / 192)), 512, 0, stream>>>(
      xb, wqkvT, qkv, S_LEN, QS, DIM);

  // one RoPE pass over q+k heads (cols 0..5119 = 40 contiguous "heads")
  rope_apply_k<<<(S_LEN * 40 * 64) / 256, 256, 0, stream>>>(qkv, QS, ct, st, 40);

  transpose_bf16_k<<<dim3(KVD / 32, S_LEN / 32), dim3(32, 8), 0, stream>>>(
      qkv + 5120, vtg, S_LEN, KVD, QS);

  attn_k<<<dim3(512), 256, 0, stream>>>(qkv, qkv + 4096, vtg, ao);

  // output projection: 128x256 2-phase counted pipeline -> grid 256 (full machine)
  gemm_wo2_k<<<dim3((S_LEN / 128) * (DIM / 256)), 512, 0, stream>>>(
      ao, woT, out, S_LEN, DIM, DIM);
}

// Round 11
// 333.063 us; speedup vs baseline: 1.7370x; 1.0316x over previous
//
#include <hip/hip_runtime.h>
#include <hip/hip_bf16.h>
#include <cstdint>
#include <cmath>

#define DIM 4096
#define NH 32
#define NKV 8
#define HD 128
#define S_LEN 2048
#define KVD (NKV * HD)   // 1024
#define QS 6144          // fused qkv row stride
#define SCALE 0.08838834764831845f

typedef __attribute__((ext_vector_type(4))) float f32x4;
typedef __attribute__((ext_vector_type(8))) short short8;

__device__ __forceinline__ short f2bf(float f) {
  union { float f; uint32_t u; } v; v.f = f;
  uint32_t u = v.u;
  u += 0x7fffu + ((u >> 16) & 1u);
  return (short)(u >> 16);
}
__device__ __forceinline__ float bf2f(short b) {
  union { uint32_t u; float f; } v; v.u = ((uint32_t)(uint16_t)b) << 16;
  return v.f;
}

__device__ __forceinline__ void async16(const void* g, void* l) {
  __builtin_amdgcn_global_load_lds(
      (__attribute__((address_space(1))) void*)(g),
      (__attribute__((address_space(3))) void*)(l), 16, 0, 0);
}

// ---------------- small prep kernels ----------------

__global__ void rope_tables_k(float* __restrict__ ct, float* __restrict__ st) {
  const int i = blockIdx.x * blockDim.x + threadIdx.x;
  if (i >= S_LEN * 64) return;
  const int s = i >> 6, d = i & 63;
  const float inv = powf(10000.0f, -(float)(2 * d) / 128.0f);
  const float fr = (float)s * inv;
  ct[i] = cosf(fr);
  st[i] = sinf(fr);
}

__global__ void cast_f32_bf16_k(const float* __restrict__ in, short* __restrict__ out, int n4) {
  const int i = blockIdx.x * blockDim.x + threadIdx.x;
  if (i >= n4) return;
  const float4 v = ((const float4*)in)[i];
  short4 o;
  o.x = f2bf(v.x); o.y = f2bf(v.y); o.z = f2bf(v.z); o.w = f2bf(v.w);
  ((short4*)out)[i] = o;
}

// fused weight prep: all four W [K=4096][N] f32 -> W^T [N][4096] bf16 in one launch.
// 64x64 tiles, block (64,4). Reads: 256 B/wave-row; writes: 128 B/wave-row.
// tile[64][65]: load conflict-free; store-side read tile[tx][c] is 2-way (free, m136).
__global__ __launch_bounds__(256) void prep_w_k(
    const float* __restrict__ wq, const float* __restrict__ wk,
    const float* __restrict__ wv, const float* __restrict__ wo,
    short* __restrict__ wqkvT, short* __restrict__ woT) {
  __shared__ float tile[64][65];
  int b = blockIdx.x;
  const float* src; short* dst; int N, bx, by;
  if (b < 4096)      { src = wq; dst = wqkvT;                        N = 4096; bx = b & 63; by = b >> 6; }
  else if (b < 5120) { b -= 4096; src = wk; dst = wqkvT + (size_t)4096 * DIM; N = 1024; bx = b & 15; by = b >> 4; }
  else if (b < 6144) { b -= 5120; src = wv; dst = wqkvT + (size_t)5120 * DIM; N = 1024; bx = b & 15; by = b >> 4; }
  else               { b -= 6144; src = wo; dst = woT;               N = 4096; bx = b & 63; by = b >> 6; }
  const int r0 = by * 64, c0 = bx * 64;
  const int tx = threadIdx.x, ty = threadIdx.y;
#pragma unroll
  for (int j = 0; j < 16; ++j)
    tile[ty + j * 4][tx] = src[(size_t)(r0 + ty + j * 4) * N + c0 + tx];
  __syncthreads();
#pragma unroll
  for (int j = 0; j < 16; ++j)
    dst[(size_t)(c0 + ty + j * 4) * DIM + r0 + tx] = f2bf(tile[tx][ty + j * 4]);
}

// bf16 transpose: in [R][C] (row stride ldi) -> out [C][R]
__global__ void transpose_bf16_k(const short* __restrict__ in, short* __restrict__ out,
                                 int R, int C, int ldi) {
  __shared__ short tile[32][33];
  const int tx = threadIdx.x, ty = threadIdx.y;
  const int c0 = blockIdx.x * 32, r0 = blockIdx.y * 32;
#pragma unroll
  for (int j = 0; j < 4; ++j)
    tile[ty + j * 8][tx] = in[(size_t)(r0 + ty + j * 8) * ldi + c0 + tx];
  __syncthreads();
#pragma unroll
  for (int j = 0; j < 4; ++j)
    out[(size_t)(c0 + ty + j * 8) * R + r0 + tx] = tile[tx][ty + j * 8];
}

// in-place RoPE on bf16 [S][*] with row stride ld; thread handles (d, d+64) pair.
// nheads=40 covers fused q (cols 0..4095) AND k (cols 4096..5119) in one pass.
__global__ void rope_apply_k(short* __restrict__ xq, int ld, const float* __restrict__ ct,
                             const float* __restrict__ st, int nheads) {
  const int i = blockIdx.x * blockDim.x + threadIdx.x;
  const int total = S_LEN * nheads * 64;
  if (i >= total) return;
  const int d = i & 63;
  const int t = i >> 6;
  const int hh = t % nheads;
  const int s = t / nheads;
  short* p = xq + (size_t)s * ld + hh * HD + d;
  const float x1 = bf2f(p[0]);
  const float x2 = bf2f(p[64]);
  const float c = ct[(s << 6) + d];
  const float sn = st[(s << 6) + d];
  p[0]  = f2bf(x1 * c - x2 * sn);
  p[64] = f2bf(x2 * c + x1 * sn);
}

// SYNC with counted vmcnt AND counted lgkmcnt.
#define SYNC2(VM, LG)                                            \
  asm volatile("s_waitcnt vmcnt(" #VM ")" ::: "memory");         \
  __builtin_amdgcn_s_barrier();                                  \
  asm volatile("s_waitcnt lgkmcnt(" #LG ")" ::: "memory");       \
  __builtin_amdgcn_sched_barrier(0);                             \
  __builtin_amdgcn_s_setprio(1)

#define PH_END()                                                 \
  __builtin_amdgcn_s_setprio(0);                                 \
  __builtin_amdgcn_sched_barrier(0);                             \
  __builtin_amdgcn_s_barrier()

// ---------------- 256x192 3-phase GEMM for QKV (bf16 out), grid = 8x32 = 256 ----------
// (R10-proven: counted vm/lg ledger, stage in reader-free window, tail peeled.)

__global__ __launch_bounds__(512, 2) void gemm192_k(
    const short* __restrict__ A, const short* __restrict__ BT,
    short* __restrict__ C, int M, int N, int K) {
  __shared__ __attribute__((aligned(16))) short ldsA[2][256 * 64];
  __shared__ __attribute__((aligned(16))) short ldsB[2][192 * 64];
  const int tid = threadIdx.x;
  const int l = tid & 63, w = tid >> 6;
  const int wrM = w >> 1, wcN = w & 1;     // 4M x 2N waves
  const int lrow = l & 15, lg = l >> 4;
  const int cofs[2] = {(lg ^ (lrow & 7)) << 3, ((4 + lg) ^ (lrow & 7)) << 3};
  (void)M;

  int bid = blockIdx.x;
  const int cpx = gridDim.x >> 3;          // XCD-chunked bijective (grid % 8 == 0)
  bid = (bid & 7) * cpx + (bid >> 3);
  const int ntn = N / 192;                 // 32
  const int m0 = (bid / ntn) << 8;
  const int n0 = (bid % ntn) * 192;

  auto stage = [&](int tau) {
    const int k0 = tau << 6;
    short* bd = &ldsB[tau & 1][0];
    short* ad = &ldsA[tau & 1][0];
#pragma unroll
    for (int it = 0; it < 3; ++it) {
      const int e = it * 512 + tid;
      const int row = e >> 3;
      const int js = (e & 7) ^ (row & 7);
      async16(BT + (size_t)(n0 + row) * K + k0 + js * 8, bd + e * 8);
    }
#pragma unroll
    for (int it = 0; it < 4; ++it) {
      const int e = it * 512 + tid;
      const int row = e >> 3;
      const int js = (e & 7) ^ (row & 7);
      async16(A + (size_t)(m0 + row) * K + k0 + js * 8, ad + e * 8);
    }
  };
  auto rdA = [&](short8 (&dst)[4][2], int b) {
    const short* p = &ldsA[b][0];
#pragma unroll
    for (int mi = 0; mi < 4; ++mi) {
      const int row = wrM * 64 + mi * 16 + lrow;
#pragma unroll
      for (int kk = 0; kk < 2; ++kk)
        dst[mi][kk] = *(const short8*)(p + row * 64 + cofs[kk]);
    }
  };
  auto rdB = [&](short8 (&dst)[2][2], int b, int pr) {
    const short* p = &ldsB[b][0];
#pragma unroll
    for (int ni = 0; ni < 2; ++ni) {
      const int row = wcN * 96 + pr * 32 + ni * 16 + lrow;
#pragma unroll
      for (int kk = 0; kk < 2; ++kk)
        dst[ni][kk] = *(const short8*)(p + row * 64 + cofs[kk]);
    }
  };

  f32x4 acc[4][6] = {};
  auto third = [&](short8 (&Af)[4][2], int pr, short8 (&Bf)[2][2]) {
#pragma unroll
    for (int kk = 0; kk < 2; ++kk)
#pragma unroll
      for (int mi = 0; mi < 4; ++mi)
#pragma unroll
        for (int ni = 0; ni < 2; ++ni)
          acc[mi][pr * 2 + ni] = __builtin_amdgcn_mfma_f32_16x16x32_bf16(
              Af[mi][kk], Bf[ni][kk], acc[mi][pr * 2 + ni], 0, 0, 0);
  };

  short8 Aa[4][2], Ab[4][2], B0f[2][2], B1f[2][2], B2f[2][2];

  // prologue: stage t0, t1; retire t0 (vm7); pre-read B0(0), A(0)
  stage(0); stage(1);
  asm volatile("s_waitcnt vmcnt(7)" ::: "memory");
  __builtin_amdgcn_s_barrier();
  rdB(B0f, 0, 0);
  rdA(Aa, 0);

  const int KT = K >> 6;  // 64 (even, >= 4)
  for (int u = 0; u < (KT - 2) / 2; ++u) {
    const int e = 2 * u;
    // ---- tile e (buf0, A=Aa) ----
    rdB(B1f, 0, 1); rdB(B2f, 0, 2);
    SYNC2(7, 8);  third(Aa, 0, B0f); PH_END();
    SYNC2(0, 0);  stage(e + 2); third(Aa, 1, B1f); PH_END();
    rdB(B0f, 1, 0); rdA(Ab, 1);
    SYNC2(7, 12); third(Aa, 2, B2f); PH_END();
    // ---- tile e+1 (buf1, A=Ab) ----
    rdB(B1f, 1, 1); rdB(B2f, 1, 2);
    SYNC2(7, 8);  third(Ab, 0, B0f); PH_END();
    SYNC2(0, 0);  stage(e + 3); third(Ab, 1, B1f); PH_END();
    rdB(B0f, 0, 0); rdA(Aa, 0);
    SYNC2(7, 12); third(Ab, 2, B2f); PH_END();
  }
  // ---- tail tile KT-2 (buf0, A=Aa): no staging ----
  rdB(B1f, 0, 1); rdB(B2f, 0, 2);
  SYNC2(7, 8);  third(Aa, 0, B0f); PH_END();     // outstanding: KT-1's 7 -> pass
  SYNC2(0, 0);  third(Aa, 1, B1f); PH_END();     // drains KT-1
  rdB(B0f, 1, 0); rdA(Ab, 1);
  SYNC2(0, 12); third(Aa, 2, B2f); PH_END();
  // ---- tile KT-1 (buf1, A=Ab): all staged data resident ----
  rdB(B1f, 1, 1); rdB(B2f, 1, 2);
  SYNC2(0, 8);  third(Ab, 0, B0f); PH_END();
  SYNC2(0, 0);  third(Ab, 1, B1f); PH_END();
  SYNC2(0, 0);  third(Ab, 2, B2f); PH_END();

  // epilogue
  const int orow0 = m0 + wrM * 64 + lg * 4;
  const int ocol0 = n0 + wcN * 96 + lrow;
#pragma unroll
  for (int mi = 0; mi < 4; ++mi)
#pragma unroll
    for (int n = 0; n < 6; ++n)
#pragma unroll
      for (int r = 0; r < 4; ++r)
        C[(size_t)(orow0 + mi * 16 + r) * N + (ocol0 + n * 16)] = f2bf(acc[mi][n][r]);
}

// ---------------- 128x256 2-phase GEMM for WO (fp32 out), grid = 16x16 = 256 ---------

__global__ __launch_bounds__(512, 2) void gemm_wo2_k(
    const short* __restrict__ A, const short* __restrict__ BT,
    float* __restrict__ C, int M, int N, int K) {
  __shared__ __attribute__((aligned(16))) short ldsA[2][128 * 64];
  __shared__ __attribute__((aligned(16))) short ldsB[2][256 * 64];
  const int tid = threadIdx.x;
  const int l = tid & 63, w = tid >> 6;
  const int wrM = w >> 2, wcN = w & 3;     // 2M x 4N waves
  const int lrow = l & 15, lg = l >> 4;
  const int cofs[2] = {(lg ^ (lrow & 7)) << 3, ((4 + lg) ^ (lrow & 7)) << 3};
  (void)M;

  int bid = blockIdx.x;
  const int cpx = gridDim.x >> 3;
  bid = (bid & 7) * cpx + (bid >> 3);
  const int ntn = N >> 8;                  // 16
  const int m0 = (bid / ntn) << 7;
  const int n0 = (bid % ntn) << 8;

  auto stage = [&](int tau) {
    const int k0 = tau << 6;
    short* ad = &ldsA[tau & 1][0];
    short* bd = &ldsB[tau & 1][0];
#pragma unroll
    for (int it = 0; it < 2; ++it) {
      const int e = it * 512 + tid;
      const int row = e >> 3;
      const int js = (e & 7) ^ (row & 7);
      async16(A + (size_t)(m0 + row) * K + k0 + js * 8, ad + e * 8);
    }
#pragma unroll
    for (int it = 0; it < 4; ++it) {
      const int e = it * 512 + tid;
      const int row = e >> 3;
      const int js = (e & 7) ^ (row & 7);
      async16(BT + (size_t)(n0 + row) * K + k0 + js * 8, bd + e * 8);
    }
  };
  auto rdA = [&](short8 (&dst)[4][2], int b) {
    const short* p = &ldsA[b][0];
#pragma unroll
    for (int mi = 0; mi < 4; ++mi) {
      const int row = wrM * 64 + mi * 16 + lrow;
#pragma unroll
      for (int kk = 0; kk < 2; ++kk)
        dst[mi][kk] = *(const short8*)(p + row * 64 + cofs[kk]);
    }
  };
  auto rdB = [&](short8 (&dst)[2][2], int b, int h) {
    const short* p = &ldsB[b][0];
#pragma unroll
    for (int ni = 0; ni < 2; ++ni) {
      const int row = wcN * 64 + h * 32 + ni * 16 + lrow;
#pragma unroll
      for (int kk = 0; kk < 2; ++kk)
        dst[ni][kk] = *(const short8*)(p + row * 64 + cofs[kk]);
    }
  };

  f32x4 acc[4][4] = {};
  auto half = [&](short8 (&Af)[4][2], int h, short8 (&Bf)[2][2]) {
#pragma unroll
    for (int kk = 0; kk < 2; ++kk)
#pragma unroll
      for (int mi = 0; mi < 4; ++mi)
#pragma unroll
        for (int ni = 0; ni < 2; ++ni)
          acc[mi][h * 2 + ni] = __builtin_amdgcn_mfma_f32_16x16x32_bf16(
              Af[mi][kk], Bf[ni][kk], acc[mi][h * 2 + ni], 0, 0, 0);
  };

  short8 Aa[4][2], Ab[4][2], H0[2][2], H1[2][2];

  // prologue
  stage(0); stage(1);
  asm volatile("s_waitcnt vmcnt(6)" ::: "memory");
  __builtin_amdgcn_s_barrier();
  rdA(Aa, 0); rdB(H0, 0, 0);

  const int KT = K >> 6;  // 64 (even, >= 4)
  for (int u = 0; u < (KT - 2) / 2; ++u) {
    const int e = 2 * u;
    // ---- tile e (buf0, A=Aa) ----
    rdB(H1, 0, 1);
    SYNC2(6, 4);  half(Aa, 0, H0); PH_END();
    SYNC2(0, 0);  stage(e + 2); rdA(Ab, 1); rdB(H0, 1, 0);
                  half(Aa, 1, H1); PH_END();
    // ---- tile e+1 (buf1, A=Ab) ----
    rdB(H1, 1, 1);
    SYNC2(6, 4);  half(Ab, 0, H0); PH_END();
    SYNC2(0, 0);  stage(e + 3); rdA(Aa, 0); rdB(H0, 0, 0);
                  half(Ab, 1, H1); PH_END();
  }
  // ---- tail tile KT-2 (buf0, A=Aa): no staging ----
  rdB(H1, 0, 1);
  SYNC2(6, 4);  half(Aa, 0, H0); PH_END();
  SYNC2(0, 0);  rdA(Ab, 1); rdB(H0, 1, 0);       // vm0 retired KT-1 first
                half(Aa, 1, H1); PH_END();
  // ---- tile KT-1 (buf1, A=Ab) ----
  rdB(H1, 1, 1);
  SYNC2(0, 4);  half(Ab, 0, H0); PH_END();
  SYNC2(0, 0);  half(Ab, 1, H1); PH_END();

  // epilogue (fp32)
  const int orow0 = m0 + wrM * 64 + lg * 4;
  const int ocol0 = n0 + wcN * 64 + lrow;
#pragma unroll
  for (int mi = 0; mi < 4; ++mi)
#pragma unroll
    for (int n = 0; n < 4; ++n)
#pragma unroll
      for (int r = 0; r < 4; ++r)
        C[(size_t)(orow0 + mi * 16 + r) * N + (ocol0 + n * 16)] = acc[mi][n][r];
}

// ---------------- flash attention (causal, GQA 4:1) ----------------

__global__ __launch_bounds__(256, 3) void attn_k(
    const short* __restrict__ Q, const short* __restrict__ Kc,
    const short* __restrict__ VTg, short* __restrict__ O) {
  __shared__ __attribute__((aligned(16))) short Ks[2][64 * 128];
  __shared__ __attribute__((aligned(16))) short Vt[2][128 * 64];
  __shared__ __attribute__((aligned(16))) short Ps[4][32 * 64];

  const int tid = threadIdx.x;
  const int w = tid >> 6, l = tid & 63;
  const int lrow = l & 15, lg = l >> 4;

  int b = blockIdx.x, h, qt;
  if (b < 256) { h = b >> 3; qt = 15 - (b & 7); }
  else { b -= 256; h = b >> 3; qt = b & 7; }
  const int kvh = h >> 2;
  const int qb0 = qt * 128;
  const int qrow0 = qb0 + w * 32;
  const int nkt = 2 * qt + 2;

  short8 qf[2][4];
#pragma unroll
  for (int nq = 0; nq < 2; ++nq) {
    const short* qp = Q + (size_t)(qrow0 + nq * 16 + lrow) * QS + h * HD;
#pragma unroll
    for (int c = 0; c < 4; ++c) qf[nq][c] = *(const short8*)(qp + c * 32 + lg * 8);
  }

  f32x4 o_acc[2][8] = {};
  float m[2] = {-INFINITY, -INFINITY};
  float lsum[2] = {0.f, 0.f};

  auto stage = [&](int kb, int buf) {
    short* kd = Ks[buf];
    short* vd = Vt[buf];
#pragma unroll
    for (int it = 0; it < 4; ++it) {
      const int e = it * 256 + tid;
      const int row = e >> 4, j = e & 15;
      const int jsrc = (j & 8) | ((j ^ row) & 7);
      async16(Kc + (size_t)(kb + row) * QS + kvh * HD + jsrc * 8, kd + e * 8);
    }
#pragma unroll
    for (int it = 0; it < 4; ++it) {
      const int e = it * 256 + tid;
      const int d = e >> 3, j = e & 7;
      const int jsrc = (j ^ d) & 7;
      async16(VTg + (size_t)(kvh * HD + d) * S_LEN + kb + jsrc * 8, vd + e * 8);
    }
  };

  stage(0, 0);
  int cur = 0;

  for (int kt = 0; kt < nkt; ++kt) {
    __syncthreads();
    if (kt + 1 < nkt) stage((kt + 1) * 64, cur ^ 1);
    const int kb = kt * 64;

    if (kb <= qrow0 + 31) {
      const char* ks = (const char*)Ks[cur];
      const char* vt = (const char*)Vt[cur];
      char* psb = (char*)Ps[w];

      f32x4 stq[4][2] = {};
#pragma unroll
      for (int c = 0; c < 4; ++c) {
#pragma unroll
        for (int mk = 0; mk < 4; ++mk) {
          const short8 kf = *(const short8*)(
              ks + (mk * 16 + lrow) * 256 + (((c * 4 + lg) ^ (lrow & 7)) << 4));
          stq[mk][0] = __builtin_amdgcn_mfma_f32_16x16x32_bf16(kf, qf[0][c], stq[mk][0], 0, 0, 0);
          stq[mk][1] = __builtin_amdgcn_mfma_f32_16x16x32_bf16(kf, qf[1][c], stq[mk][1], 0, 0, 0);
        }
      }

      const bool needmask = (kb + 63 > qrow0);
#pragma unroll
      for (int mk = 0; mk < 4; ++mk)
#pragma unroll
        for (int nq = 0; nq < 2; ++nq)
#pragma unroll
          for (int r = 0; r < 4; ++r) {
            float v = stq[mk][nq][r] * SCALE;
            if (needmask && (kb + mk * 16 + lg * 4 + r > qrow0 + nq * 16 + lrow))
              v = -INFINITY;
            stq[mk][nq][r] = v;
          }

      float vmax[2];
#pragma unroll
      for (int nq = 0; nq < 2; ++nq) {
        float v = stq[0][nq][0];
#pragma unroll
        for (int mk = 0; mk < 4; ++mk)
#pragma unroll
          for (int r = 0; r < 4; ++r) v = fmaxf(v, stq[mk][nq][r]);
        v = fmaxf(v, __shfl_xor(v, 16));
        v = fmaxf(v, __shfl_xor(v, 32));
        vmax[nq] = v;
      }

      const int small = (vmax[0] <= m[0] + 8.0f) && (vmax[1] <= m[1] + 8.0f);
      if (!__all(small)) {
        float al[2];
#pragma unroll
        for (int nq = 0; nq < 2; ++nq) {
          const float mn = fmaxf(m[nq], vmax[nq]);
          al[nq] = __expf(m[nq] - mn);
          m[nq] = mn;
          lsum[nq] *= al[nq];
        }
#pragma unroll
        for (int mmq = 0; mmq < 2; ++mmq)
#pragma unroll
          for (int r = 0; r < 4; ++r) {
            const float a = __shfl(al[mmq], lg * 4 + r);
#pragma unroll
            for (int d = 0; d < 8; ++d) o_acc[mmq][d][r] *= a;
          }
      }

      float rs[2] = {0.f, 0.f};
#pragma unroll
      for (int nq = 0; nq < 2; ++nq) {
#pragma unroll
        for (int mk = 0; mk < 4; ++mk) {
          const float p0 = __expf(stq[mk][nq][0] - m[nq]);
          const float p1 = __expf(stq[mk][nq][1] - m[nq]);
          const float p2 = __expf(stq[mk][nq][2] - m[nq]);
          const float p3 = __expf(stq[mk][nq][3] - m[nq]);
          rs[nq] += (p0 + p1) + (p2 + p3);
          __hip_bfloat16 b0 = __float2bfloat16(p0), b1 = __float2bfloat16(p1);
          __hip_bfloat16 b2 = __float2bfloat16(p2), b3 = __float2bfloat16(p3);
          short4 pk;
          pk.x = *(short*)&b0; pk.y = *(short*)&b1; pk.z = *(short*)&b2; pk.w = *(short*)&b3;
          const int q = nq * 16 + lrow;
          *(short4*)(psb + q * 128 + ((mk * 32 + lg * 8) ^ ((q & 7) << 4))) = pk;
        }
        float r2 = rs[nq];
        r2 += __shfl_xor(r2, 16);
        r2 += __shfl_xor(r2, 32);
        lsum[nq] += r2;
      }

#pragma unroll
      for (int cc = 0; cc < 2; ++cc) {
        const int chunk = ((cc * 4 + lg) ^ (lrow & 7)) << 4;
        const short8 pa0 = *(const short8*)(psb + lrow * 128 + chunk);
        const short8 pa1 = *(const short8*)(psb + (16 + lrow) * 128 + chunk);
#pragma unroll
        for (int d = 0; d < 8; ++d) {
          const short8 vf = *(const short8*)(vt + (d * 16 + lrow) * 128 + chunk);
          o_acc[0][d] = __builtin_amdgcn_mfma_f32_16x16x32_bf16(pa0, vf, o_acc[0][d], 0, 0, 0);
          o_acc[1][d] = __builtin_amdgcn_mfma_f32_16x16x32_bf16(pa1, vf, o_acc[1][d], 0, 0, 0);
        }
      }
    }
    cur ^= 1;
  }

  float linv[2] = {1.0f / lsum[0], 1.0f / lsum[1]};
#pragma unroll
  for (int mmq = 0; mmq < 2; ++mmq)
#pragma unroll
    for (int r = 0; r < 4; ++r) {
      const float li = __shfl(linv[mmq], lg * 4 + r);
      short* op = O + (size_t)(qrow0 + mmq * 16 + lg * 4 + r) * DIM + h * HD;
#pragma unroll
      for (int d = 0; d < 8; ++d)
        op[d * 16 + lrow] = f2bf(o_acc[mmq][d][r] * li);
    }
}

// ---------------- launch ----------------

extern "C" void kernel_launch(void* const* d_in, const int* in_sizes, int n_in,
                              void* d_out, int out_size, void* d_ws, size_t ws_size,
                              hipStream_t stream) {
  const float* x  = (const float*)d_in[0];
  const float* wq = (const float*)d_in[1];
  const float* wk = (const float*)d_in[2];
  const float* wv = (const float*)d_in[3];
  const float* wo = (const float*)d_in[4];
  float* out = (float*)d_out;
  (void)in_sizes; (void)n_in; (void)out_size; (void)ws_size;

  char* ws = (char*)d_ws;
  size_t off = 0;
  auto alloc = [&](size_t bytes) -> void* {
    void* p = ws + off;
    off += (bytes + 255) & ~(size_t)255;
    return p;
  };
  short* xb     = (short*)alloc((size_t)S_LEN * DIM * 2);
  short* wqkvT  = (short*)alloc((size_t)QS * DIM * 2);     // [6144][4096]
  short* woT    = (short*)alloc((size_t)DIM * DIM * 2);
  short* qkv    = (short*)alloc((size_t)S_LEN * QS * 2);   // [2048][6144]
  short* vtg    = (short*)alloc((size_t)KVD * S_LEN * 2);  // [1024][2048]
  short* ao     = (short*)alloc((size_t)S_LEN * DIM * 2);
  float* ct     = (float*)alloc((size_t)S_LEN * 64 * 4);
  float* st     = (float*)alloc((size_t)S_LEN * 64 * 4);

  rope_tables_k<<<(S_LEN * 64) / 256, 256, 0, stream>>>(ct, st);
  cast_f32_bf16_k<<<(S_LEN * DIM / 4) / 256, 256, 0, stream>>>(x, xb, S_LEN * DIM / 4);
  // all four weight transposes in one vectorized launch (10240 x 64x64 tiles)
  prep_w_k<<<dim3(10240), dim3(64, 4), 0, stream>>>(wq, wk, wv, wo, wqkvT, woT);

  // fused QKV projection: [2048][6144], 256x192 tiles -> grid 256 (full machine)
  gemm192_k<<<dim3((S_LEN / 256) * (QS / 192)), 512, 0, stream>>>(
      xb, wqkvT, qkv, S_LEN, QS, DIM);

  // one RoPE pass over q+k heads (cols 0..5119 = 40 contiguous "heads")
  rope_apply_k<<<(S_LEN * 40 * 64) / 256, 256, 0, stream>>>(qkv, QS, ct, st, 40);

  transpose_bf16_k<<<dim3(KVD / 32, S_LEN / 32), dim3(32, 8), 0, stream>>>(
      qkv + 5120, vtg, S_LEN, KVD, QS);

  attn_k<<<dim3(512), 256, 0, stream>>>(qkv, qkv + 4096, vtg, ao);

  // output projection: 128x256 2-phase counted pipeline -> grid 256 (full machine)
  gemm_wo2_k<<<dim3((S_LEN / 128) * (DIM / 256)), 512, 0, stream>>>(
      ao, woT, out, S_LEN, DIM, DIM);
}

// Round 12
// 318.199 us; speedup vs baseline: 1.8181x; 1.0467x over previous
//
#include <hip/hip_runtime.h>
#include <hip/hip_bf16.h>
#include <cstdint>
#include <cmath>

#define DIM 4096
#define NH 32
#define NKV 8
#define HD 128
#define S_LEN 2048
#define KVD (NKV * HD)   // 1024
#define QS 6144          // fused qkv row stride
#define SCALE 0.08838834764831845f

typedef __attribute__((ext_vector_type(4))) float f32x4;
typedef __attribute__((ext_vector_type(8))) short short8;

__device__ __forceinline__ short f2bf(float f) {
  union { float f; uint32_t u; } v; v.f = f;
  uint32_t u = v.u;
  u += 0x7fffu + ((u >> 16) & 1u);
  return (short)(u >> 16);
}
__device__ __forceinline__ float bf2f(short b) {
  union { uint32_t u; float f; } v; v.u = ((uint32_t)(uint16_t)b) << 16;
  return v.f;
}

__device__ __forceinline__ void async16(const void* g, void* l) {
  __builtin_amdgcn_global_load_lds(
      (__attribute__((address_space(1))) void*)(g),
      (__attribute__((address_space(3))) void*)(l), 16, 0, 0);
}

// ---------------- small prep kernels ----------------

__global__ void rope_tables_k(float* __restrict__ ct, float* __restrict__ st) {
  const int i = blockIdx.x * blockDim.x + threadIdx.x;
  if (i >= S_LEN * 64) return;
  const int s = i >> 6, d = i & 63;
  const float inv = powf(10000.0f, -(float)(2 * d) / 128.0f);
  const float fr = (float)s * inv;
  ct[i] = cosf(fr);
  st[i] = sinf(fr);
}

__global__ void cast_f32_bf16_k(const float* __restrict__ in, short* __restrict__ out, int n4) {
  const int i = blockIdx.x * blockDim.x + threadIdx.x;
  if (i >= n4) return;
  const float4 v = ((const float4*)in)[i];
  short4 o;
  o.x = f2bf(v.x); o.y = f2bf(v.y); o.z = f2bf(v.z); o.w = f2bf(v.w);
  ((short4*)out)[i] = o;
}

// fused weight prep: all four W [K=4096][N] f32 -> W^T [N][4096] bf16 in one launch.
__global__ __launch_bounds__(256) void prep_w_k(
    const float* __restrict__ wq, const float* __restrict__ wk,
    const float* __restrict__ wv, const float* __restrict__ wo,
    short* __restrict__ wqkvT, short* __restrict__ woT) {
  __shared__ float tile[64][65];
  int b = blockIdx.x;
  const float* src; short* dst; int N, bx, by;
  if (b < 4096)      { src = wq; dst = wqkvT;                        N = 4096; bx = b & 63; by = b >> 6; }
  else if (b < 5120) { b -= 4096; src = wk; dst = wqkvT + (size_t)4096 * DIM; N = 1024; bx = b & 15; by = b >> 4; }
  else if (b < 6144) { b -= 5120; src = wv; dst = wqkvT + (size_t)5120 * DIM; N = 1024; bx = b & 15; by = b >> 4; }
  else               { b -= 6144; src = wo; dst = woT;               N = 4096; bx = b & 63; by = b >> 6; }
  const int r0 = by * 64, c0 = bx * 64;
  const int tx = threadIdx.x, ty = threadIdx.y;
#pragma unroll
  for (int j = 0; j < 16; ++j)
    tile[ty + j * 4][tx] = src[(size_t)(r0 + ty + j * 4) * N + c0 + tx];
  __syncthreads();
#pragma unroll
  for (int j = 0; j < 16; ++j)
    dst[(size_t)(c0 + ty + j * 4) * DIM + r0 + tx] = f2bf(tile[tx][ty + j * 4]);
}

// bf16 transpose: in [R][C] (row stride ldi) -> out [C][R]
__global__ void transpose_bf16_k(const short* __restrict__ in, short* __restrict__ out,
                                 int R, int C, int ldi) {
  __shared__ short tile[32][33];
  const int tx = threadIdx.x, ty = threadIdx.y;
  const int c0 = blockIdx.x * 32, r0 = blockIdx.y * 32;
#pragma unroll
  for (int j = 0; j < 4; ++j)
    tile[ty + j * 8][tx] = in[(size_t)(r0 + ty + j * 8) * ldi + c0 + tx];
  __syncthreads();
#pragma unroll
  for (int j = 0; j < 4; ++j)
    out[(size_t)(c0 + ty + j * 8) * R + r0 + tx] = tile[tx][ty + j * 8];
}

// in-place RoPE on bf16 [S][*] with row stride ld; nheads=40 covers q+k in one pass.
__global__ void rope_apply_k(short* __restrict__ xq, int ld, const float* __restrict__ ct,
                             const float* __restrict__ st, int nheads) {
  const int i = blockIdx.x * blockDim.x + threadIdx.x;
  const int total = S_LEN * nheads * 64;
  if (i >= total) return;
  const int d = i & 63;
  const int t = i >> 6;
  const int hh = t % nheads;
  const int s = t / nheads;
  short* p = xq + (size_t)s * ld + hh * HD + d;
  const float x1 = bf2f(p[0]);
  const float x2 = bf2f(p[64]);
  const float c = ct[(s << 6) + d];
  const float sn = st[(s << 6) + d];
  p[0]  = f2bf(x1 * c - x2 * sn);
  p[64] = f2bf(x2 * c + x1 * sn);
}

// SYNC with counted vmcnt AND counted lgkmcnt.
#define SYNC2(VM, LG)                                            \
  asm volatile("s_waitcnt vmcnt(" #VM ")" ::: "memory");         \
  __builtin_amdgcn_s_barrier();                                  \
  asm volatile("s_waitcnt lgkmcnt(" #LG ")" ::: "memory");       \
  __builtin_amdgcn_sched_barrier(0);                             \
  __builtin_amdgcn_s_setprio(1)

#define PH_END()                                                 \
  __builtin_amdgcn_s_setprio(0);                                 \
  __builtin_amdgcn_sched_barrier(0);                             \
  __builtin_amdgcn_s_barrier()

// ---------------- 256x192 2-PHASE GEMM for QKV (bf16 out), grid = 8x32 = 256 ---------
// 8 waves (4M x 2N), per-wave C = 64x96 (acc[4][6]). BK=64, dbuf LDS 112KB, XOR swizzle.
// B's 6 n-frags split 48+48: BF (n0..2), BS (n3..5), both single-set (lifetimes:
// BF(t) last use p0(t), rewritten p1(t); BS(t) read p0(t), used p1(t), reread p0(t+1)).
// A double-buffered (Aa even tiles, Ab odd).
// Phase plan, tile t (buf c=t&1), 24 MFMA each:
//  p0: [pre] rd BS(t) (6)   | SYNC(vm7 pass [A(t+1)4+B(t+1)3 in flight], lg6: retires
//      the 14 rds of A(t)+BF(t) from p1(t-1))  | [post] stageA(t+2) (4 gl; A-buf c dead:
//      A(t) rds just retired)                   | MFMA A(t) x BF(t)
//  p1: SYNC(vm4: outstanding A(t+1)4+B(t+1)3+A(t+2)4=11 -> retires exactly tile t+1;
//      lg0: retires BS(t))                      | [post] stageB(t+2) (3 gl; B-buf c dead:
//      BF(t) retired at p0, BS(t) at this lg0) + rd A(t+1)(8)+BF(t+1)(6) [t+1 resident]
//                                               | MFMA A(t) x BS(t)
// Flights: A-stage 3 phases, B-stage 2. Tail peeled: no stage at KT-2 -> p1 vm(0)
// drains KT-1 (the R6 lesson); KT-1 all-resident.

__global__ __launch_bounds__(512, 2) void gemm192_k(
    const short* __restrict__ A, const short* __restrict__ BT,
    short* __restrict__ C, int M, int N, int K) {
  __shared__ __attribute__((aligned(16))) short ldsA[2][256 * 64];
  __shared__ __attribute__((aligned(16))) short ldsB[2][192 * 64];
  const int tid = threadIdx.x;
  const int l = tid & 63, w = tid >> 6;
  const int wrM = w >> 1, wcN = w & 1;     // 4M x 2N waves
  const int lrow = l & 15, lg = l >> 4;
  const int cofs[2] = {(lg ^ (lrow & 7)) << 3, ((4 + lg) ^ (lrow & 7)) << 3};
  (void)M;

  int bid = blockIdx.x;
  const int cpx = gridDim.x >> 3;          // XCD-chunked bijective (grid % 8 == 0)
  bid = (bid & 7) * cpx + (bid >> 3);
  const int ntn = N / 192;                 // 32
  const int m0 = (bid / ntn) << 8;
  const int n0 = (bid % ntn) * 192;

  auto stageA = [&](int tau) {
    const int k0 = tau << 6;
    short* ad = &ldsA[tau & 1][0];
#pragma unroll
    for (int it = 0; it < 4; ++it) {
      const int e = it * 512 + tid;
      const int row = e >> 3;
      const int js = (e & 7) ^ (row & 7);
      async16(A + (size_t)(m0 + row) * K + k0 + js * 8, ad + e * 8);
    }
  };
  auto stageB = [&](int tau) {
    const int k0 = tau << 6;
    short* bd = &ldsB[tau & 1][0];
#pragma unroll
    for (int it = 0; it < 3; ++it) {
      const int e = it * 512 + tid;
      const int row = e >> 3;
      const int js = (e & 7) ^ (row & 7);
      async16(BT + (size_t)(n0 + row) * K + k0 + js * 8, bd + e * 8);
    }
  };
  auto rdA = [&](short8 (&dst)[4][2], int b) {
    const short* p = &ldsA[b][0];
#pragma unroll
    for (int mi = 0; mi < 4; ++mi) {
      const int row = wrM * 64 + mi * 16 + lrow;
#pragma unroll
      for (int kk = 0; kk < 2; ++kk)
        dst[mi][kk] = *(const short8*)(p + row * 64 + cofs[kk]);
    }
  };
  auto rdB3 = [&](short8 (&dst)[3][2], int b, int h) {
    const short* p = &ldsB[b][0];
#pragma unroll
    for (int ni = 0; ni < 3; ++ni) {
      const int row = wcN * 96 + h * 48 + ni * 16 + lrow;
#pragma unroll
      for (int kk = 0; kk < 2; ++kk)
        dst[ni][kk] = *(const short8*)(p + row * 64 + cofs[kk]);
    }
  };

  f32x4 acc[4][6] = {};
  auto half24 = [&](short8 (&Af)[4][2], int h, short8 (&Bf)[3][2]) {
#pragma unroll
    for (int kk = 0; kk < 2; ++kk)
#pragma unroll
      for (int mi = 0; mi < 4; ++mi)
#pragma unroll
        for (int ni = 0; ni < 3; ++ni)
          acc[mi][h * 3 + ni] = __builtin_amdgcn_mfma_f32_16x16x32_bf16(
              Af[mi][kk], Bf[ni][kk], acc[mi][h * 3 + ni], 0, 0, 0);
  };

  short8 Aa[4][2], Ab[4][2], BF[3][2], BS[3][2];

  // prologue: stage t0 (A4,B3), t1 (A4,B3); vm(7) retires t0; pre-read A(0), BF(0)
  stageA(0); stageB(0); stageA(1); stageB(1);
  asm volatile("s_waitcnt vmcnt(7)" ::: "memory");
  __builtin_amdgcn_s_barrier();
  rdA(Aa, 0); rdB3(BF, 0, 0);

  const int KT = K >> 6;  // 64 (even, >= 4)
  for (int u = 0; u < (KT - 2) / 2; ++u) {
    const int e = 2 * u;
    // ---- tile e (buf0, A=Aa) ----
    rdB3(BS, 0, 1);
    SYNC2(7, 6);  stageA(e + 2); half24(Aa, 0, BF); PH_END();
    SYNC2(4, 0);  stageB(e + 2); rdA(Ab, 1); rdB3(BF, 1, 0);
                  half24(Aa, 1, BS); PH_END();
    // ---- tile e+1 (buf1, A=Ab) ----
    rdB3(BS, 1, 1);
    SYNC2(7, 6);  stageA(e + 3); half24(Ab, 0, BF); PH_END();
    SYNC2(4, 0);  stageB(e + 3); rdA(Aa, 0); rdB3(BF, 0, 0);
                  half24(Ab, 1, BS); PH_END();
  }
  // ---- tail tile KT-2 (buf0, A=Aa): no staging ----
  rdB3(BS, 0, 1);
  SYNC2(7, 6);  half24(Aa, 0, BF); PH_END();     // outstanding: KT-1's 7 -> pass
  SYNC2(0, 0);  rdA(Ab, 1); rdB3(BF, 1, 0);      // vm0 drains KT-1 first
                half24(Aa, 1, BS); PH_END();
  // ---- tile KT-1 (buf1, A=Ab): all resident ----
  rdB3(BS, 1, 1);
  SYNC2(0, 6);  half24(Ab, 0, BF); PH_END();
  SYNC2(0, 0);  half24(Ab, 1, BS); PH_END();

  // epilogue
  const int orow0 = m0 + wrM * 64 + lg * 4;
  const int ocol0 = n0 + wcN * 96 + lrow;
#pragma unroll
  for (int mi = 0; mi < 4; ++mi)
#pragma unroll
    for (int n = 0; n < 6; ++n)
#pragma unroll
      for (int r = 0; r < 4; ++r)
        C[(size_t)(orow0 + mi * 16 + r) * N + (ocol0 + n * 16)] = f2bf(acc[mi][n][r]);
}

// ---------------- 128x256 2-phase GEMM for WO (fp32 out), grid = 16x16 = 256 ---------
// R10-proven + stage-split: A-part (2 gl) at p0 (3-phase flight), B-part (4 gl) at p1.

__global__ __launch_bounds__(512, 2) void gemm_wo2_k(
    const short* __restrict__ A, const short* __restrict__ BT,
    float* __restrict__ C, int M, int N, int K) {
  __shared__ __attribute__((aligned(16))) short ldsA[2][128 * 64];
  __shared__ __attribute__((aligned(16))) short ldsB[2][256 * 64];
  const int tid = threadIdx.x;
  const int l = tid & 63, w = tid >> 6;
  const int wrM = w >> 2, wcN = w & 3;     // 2M x 4N waves
  const int lrow = l & 15, lg = l >> 4;
  const int cofs[2] = {(lg ^ (lrow & 7)) << 3, ((4 + lg) ^ (lrow & 7)) << 3};
  (void)M;

  int bid = blockIdx.x;
  const int cpx = gridDim.x >> 3;
  bid = (bid & 7) * cpx + (bid >> 3);
  const int ntn = N >> 8;                  // 16
  const int m0 = (bid / ntn) << 7;
  const int n0 = (bid % ntn) << 8;

  auto stageA2 = [&](int tau) {
    const int k0 = tau << 6;
    short* ad = &ldsA[tau & 1][0];
#pragma unroll
    for (int it = 0; it < 2; ++it) {
      const int e = it * 512 + tid;
      const int row = e >> 3;
      const int js = (e & 7) ^ (row & 7);
      async16(A + (size_t)(m0 + row) * K + k0 + js * 8, ad + e * 8);
    }
  };
  auto stageB2 = [&](int tau) {
    const int k0 = tau << 6;
    short* bd = &ldsB[tau & 1][0];
#pragma unroll
    for (int it = 0; it < 4; ++it) {
      const int e = it * 512 + tid;
      const int row = e >> 3;
      const int js = (e & 7) ^ (row & 7);
      async16(BT + (size_t)(n0 + row) * K + k0 + js * 8, bd + e * 8);
    }
  };
  auto rdA = [&](short8 (&dst)[4][2], int b) {
    const short* p = &ldsA[b][0];
#pragma unroll
    for (int mi = 0; mi < 4; ++mi) {
      const int row = wrM * 64 + mi * 16 + lrow;
#pragma unroll
      for (int kk = 0; kk < 2; ++kk)
        dst[mi][kk] = *(const short8*)(p + row * 64 + cofs[kk]);
    }
  };
  auto rdB = [&](short8 (&dst)[2][2], int b, int h) {
    const short* p = &ldsB[b][0];
#pragma unroll
    for (int ni = 0; ni < 2; ++ni) {
      const int row = wcN * 64 + h * 32 + ni * 16 + lrow;
#pragma unroll
      for (int kk = 0; kk < 2; ++kk)
        dst[ni][kk] = *(const short8*)(p + row * 64 + cofs[kk]);
    }
  };

  f32x4 acc[4][4] = {};
  auto half = [&](short8 (&Af)[4][2], int h, short8 (&Bf)[2][2]) {
#pragma unroll
    for (int kk = 0; kk < 2; ++kk)
#pragma unroll
      for (int mi = 0; mi < 4; ++mi)
#pragma unroll
        for (int ni = 0; ni < 2; ++ni)
          acc[mi][h * 2 + ni] = __builtin_amdgcn_mfma_f32_16x16x32_bf16(
              Af[mi][kk], Bf[ni][kk], acc[mi][h * 2 + ni], 0, 0, 0);
  };

  short8 Aa[4][2], Ab[4][2], H0[2][2], H1[2][2];

  // prologue
  stageA2(0); stageB2(0); stageA2(1); stageB2(1);
  asm volatile("s_waitcnt vmcnt(6)" ::: "memory");
  __builtin_amdgcn_s_barrier();
  rdA(Aa, 0); rdB(H0, 0, 0);

  const int KT = K >> 6;  // 64 (even, >= 4)
  for (int u = 0; u < (KT - 2) / 2; ++u) {
    const int e = 2 * u;
    // ---- tile e (buf0, A=Aa) ----
    rdB(H1, 0, 1);
    SYNC2(6, 4);  stageA2(e + 2); half(Aa, 0, H0); PH_END();
    SYNC2(2, 0);  stageB2(e + 2); rdA(Ab, 1); rdB(H0, 1, 0);
                  half(Aa, 1, H1); PH_END();
    // ---- tile e+1 (buf1, A=Ab) ----
    rdB(H1, 1, 1);
    SYNC2(6, 4);  stageA2(e + 3); half(Ab, 0, H0); PH_END();
    SYNC2(2, 0);  stageB2(e + 3); rdA(Aa, 0); rdB(H0, 0, 0);
                  half(Ab, 1, H1); PH_END();
  }
  // ---- tail tile KT-2 (buf0, A=Aa): no staging ----
  rdB(H1, 0, 1);
  SYNC2(6, 4);  half(Aa, 0, H0); PH_END();
  SYNC2(0, 0);  rdA(Ab, 1); rdB(H0, 1, 0);       // vm0 retired KT-1 first
                half(Aa, 1, H1); PH_END();
  // ---- tile KT-1 (buf1, A=Ab) ----
  rdB(H1, 1, 1);
  SYNC2(0, 4);  half(Ab, 0, H0); PH_END();
  SYNC2(0, 0);  half(Ab, 1, H1); PH_END();

  // epilogue (fp32)
  const int orow0 = m0 + wrM * 64 + lg * 4;
  const int ocol0 = n0 + wcN * 64 + lrow;
#pragma unroll
  for (int mi = 0; mi < 4; ++mi)
#pragma unroll
    for (int n = 0; n < 4; ++n)
#pragma unroll
      for (int r = 0; r < 4; ++r)
        C[(size_t)(orow0 + mi * 16 + r) * N + (ocol0 + n * 16)] = acc[mi][n][r];
}

// ---------------- flash attention (causal, GQA 4:1) ----------------

__global__ __launch_bounds__(256, 3) void attn_k(
    const short* __restrict__ Q, const short* __restrict__ Kc,
    const short* __restrict__ VTg, short* __restrict__ O) {
  __shared__ __attribute__((aligned(16))) short Ks[2][64 * 128];
  __shared__ __attribute__((aligned(16))) short Vt[2][128 * 64];
  __shared__ __attribute__((aligned(16))) short Ps[4][32 * 64];

  const int tid = threadIdx.x;
  const int w = tid >> 6, l = tid & 63;
  const int lrow = l & 15, lg = l >> 4;

  int b = blockIdx.x, h, qt;
  if (b < 256) { h = b >> 3; qt = 15 - (b & 7); }
  else { b -= 256; h = b >> 3; qt = b & 7; }
  const int kvh = h >> 2;
  const int qb0 = qt * 128;
  const int qrow0 = qb0 + w * 32;
  const int nkt = 2 * qt + 2;

  short8 qf[2][4];
#pragma unroll
  for (int nq = 0; nq < 2; ++nq) {
    const short* qp = Q + (size_t)(qrow0 + nq * 16 + lrow) * QS + h * HD;
#pragma unroll
    for (int c = 0; c < 4; ++c) qf[nq][c] = *(const short8*)(qp + c * 32 + lg * 8);
  }

  f32x4 o_acc[2][8] = {};
  float m[2] = {-INFINITY, -INFINITY};
  float lsum[2] = {0.f, 0.f};

  auto stage = [&](int kb, int buf) {
    short* kd = Ks[buf];
    short* vd = Vt[buf];
#pragma unroll
    for (int it = 0; it < 4; ++it) {
      const int e = it * 256 + tid;
      const int row = e >> 4, j = e & 15;
      const int jsrc = (j & 8) | ((j ^ row) & 7);
      async16(Kc + (size_t)(kb + row) * QS + kvh * HD + jsrc * 8, kd + e * 8);
    }
#pragma unroll
    for (int it = 0; it < 4; ++it) {
      const int e = it * 256 + tid;
      const int d = e >> 3, j = e & 7;
      const int jsrc = (j ^ d) & 7;
      async16(VTg + (size_t)(kvh * HD + d) * S_LEN + kb + jsrc * 8, vd + e * 8);
    }
  };

  stage(0, 0);
  int cur = 0;

  for (int kt = 0; kt < nkt; ++kt) {
    __syncthreads();
    if (kt + 1 < nkt) stage((kt + 1) * 64, cur ^ 1);
    const int kb = kt * 64;

    if (kb <= qrow0 + 31) {
      const char* ks = (const char*)Ks[cur];
      const char* vt = (const char*)Vt[cur];
      char* psb = (char*)Ps[w];

      f32x4 stq[4][2] = {};
#pragma unroll
      for (int c = 0; c < 4; ++c) {
#pragma unroll
        for (int mk = 0; mk < 4; ++mk) {
          const short8 kf = *(const short8*)(
              ks + (mk * 16 + lrow) * 256 + (((c * 4 + lg) ^ (lrow & 7)) << 4));
          stq[mk][0] = __builtin_amdgcn_mfma_f32_16x16x32_bf16(kf, qf[0][c], stq[mk][0], 0, 0, 0);
          stq[mk][1] = __builtin_amdgcn_mfma_f32_16x16x32_bf16(kf, qf[1][c], stq[mk][1], 0, 0, 0);
        }
      }

      const bool needmask = (kb + 63 > qrow0);
#pragma unroll
      for (int mk = 0; mk < 4; ++mk)
#pragma unroll
        for (int nq = 0; nq < 2; ++nq)
#pragma unroll
          for (int r = 0; r < 4; ++r) {
            float v = stq[mk][nq][r] * SCALE;
            if (needmask && (kb + mk * 16 + lg * 4 + r > qrow0 + nq * 16 + lrow))
              v = -INFINITY;
            stq[mk][nq][r] = v;
          }

      float vmax[2];
#pragma unroll
      for (int nq = 0; nq < 2; ++nq) {
        float v = stq[0][nq][0];
#pragma unroll
        for (int mk = 0; mk < 4; ++mk)
#pragma unroll
          for (int r = 0; r < 4; ++r) v = fmaxf(v, stq[mk][nq][r]);
        v = fmaxf(v, __shfl_xor(v, 16));
        v = fmaxf(v, __shfl_xor(v, 32));
        vmax[nq] = v;
      }

      const int small = (vmax[0] <= m[0] + 8.0f) && (vmax[1] <= m[1] + 8.0f);
      if (!__all(small)) {
        float al[2];
#pragma unroll
        for (int nq = 0; nq < 2; ++nq) {
          const float mn = fmaxf(m[nq], vmax[nq]);
          al[nq] = __expf(m[nq] - mn);
          m[nq] = mn;
          lsum[nq] *= al[nq];
        }
#pragma unroll
        for (int mmq = 0; mmq < 2; ++mmq)
#pragma unroll
          for (int r = 0; r < 4; ++r) {
            const float a = __shfl(al[mmq], lg * 4 + r);
#pragma unroll
            for (int d = 0; d < 8; ++d) o_acc[mmq][d][r] *= a;
          }
      }

      float rs[2] = {0.f, 0.f};
#pragma unroll
      for (int nq = 0; nq < 2; ++nq) {
#pragma unroll
        for (int mk = 0; mk < 4; ++mk) {
          const float p0 = __expf(stq[mk][nq][0] - m[nq]);
          const float p1 = __expf(stq[mk][nq][1] - m[nq]);
          const float p2 = __expf(stq[mk][nq][2] - m[nq]);
          const float p3 = __expf(stq[mk][nq][3] - m[nq]);
          rs[nq] += (p0 + p1) + (p2 + p3);
          __hip_bfloat16 b0 = __float2bfloat16(p0), b1 = __float2bfloat16(p1);
          __hip_bfloat16 b2 = __float2bfloat16(p2), b3 = __float2bfloat16(p3);
          short4 pk;
          pk.x = *(short*)&b0; pk.y = *(short*)&b1; pk.z = *(short*)&b2; pk.w = *(short*)&b3;
          const int q = nq * 16 + lrow;
          *(short4*)(psb + q * 128 + ((mk * 32 + lg * 8) ^ ((q & 7) << 4))) = pk;
        }
        float r2 = rs[nq];
        r2 += __shfl_xor(r2, 16);
        r2 += __shfl_xor(r2, 32);
        lsum[nq] += r2;
      }

#pragma unroll
      for (int cc = 0; cc < 2; ++cc) {
        const int chunk = ((cc * 4 + lg) ^ (lrow & 7)) << 4;
        const short8 pa0 = *(const short8*)(psb + lrow * 128 + chunk);
        const short8 pa1 = *(const short8*)(psb + (16 + lrow) * 128 + chunk);
#pragma unroll
        for (int d = 0; d < 8; ++d) {
          const short8 vf = *(const short8*)(vt + (d * 16 + lrow) * 128 + chunk);
          o_acc[0][d] = __builtin_amdgcn_mfma_f32_16x16x32_bf16(pa0, vf, o_acc[0][d], 0, 0, 0);
          o_acc[1][d] = __builtin_amdgcn_mfma_f32_16x16x32_bf16(pa1, vf, o_acc[1][d], 0, 0, 0);
        }
      }
    }
    cur ^= 1;
  }

  float linv[2] = {1.0f / lsum[0], 1.0f / lsum[1]};
#pragma unroll
  for (int mmq = 0; mmq < 2; ++mmq)
#pragma unroll
    for (int r = 0; r < 4; ++r) {
      const float li = __shfl(linv[mmq], lg * 4 + r);
      short* op = O + (size_t)(qrow0 + mmq * 16 + lg * 4 + r) * DIM + h * HD;
#pragma unroll
      for (int d = 0; d < 8; ++d)
        op[d * 16 + lrow] = f2bf(o_acc[mmq][d][r] * li);
    }
}

// ---------------- launch ----------------

extern "C" void kernel_launch(void* const* d_in, const int* in_sizes, int n_in,
                              void* d_out, int out_size, void* d_ws, size_t ws_size,
                              hipStream_t stream) {
  const float* x  = (const float*)d_in[0];
  const float* wq = (const float*)d_in[1];
  const float* wk = (const float*)d_in[2];
  const float* wv = (const float*)d_in[3];
  const float* wo = (const float*)d_in[4];
  float* out = (float*)d_out;
  (void)in_sizes; (void)n_in; (void)out_size; (void)ws_size;

  char* ws = (char*)d_ws;
  size_t off = 0;
  auto alloc = [&](size_t bytes) -> void* {
    void* p = ws + off;
    off += (bytes + 255) & ~(size_t)255;
    return p;
  };
  short* xb     = (short*)alloc((size_t)S_LEN * DIM * 2);
  short* wqkvT  = (short*)alloc((size_t)QS * DIM * 2);     // [6144][4096]
  short* woT    = (short*)alloc((size_t)DIM * DIM * 2);
  short* qkv    = (short*)alloc((size_t)S_LEN * QS * 2);   // [2048][6144]
  short* vtg    = (short*)alloc((size_t)KVD * S_LEN * 2);  // [1024][2048]
  short* ao     = (short*)alloc((size_t)S_LEN * DIM * 2);
  float* ct     = (float*)alloc((size_t)S_LEN * 64 * 4);
  float* st     = (float*)alloc((size_t)S_LEN * 64 * 4);

  rope_tables_k<<<(S_LEN * 64) / 256, 256, 0, stream>>>(ct, st);
  cast_f32_bf16_k<<<(S_LEN * DIM / 4) / 256, 256, 0, stream>>>(x, xb, S_LEN * DIM / 4);
  prep_w_k<<<dim3(10240), dim3(64, 4), 0, stream>>>(wq, wk, wv, wo, wqkvT, woT);

  // fused QKV projection: [2048][6144], 256x192 2-phase -> grid 256 (full machine)
  gemm192_k<<<dim3((S_LEN / 256) * (QS / 192)), 512, 0, stream>>>(
      xb, wqkvT, qkv, S_LEN, QS, DIM);

  rope_apply_k<<<(S_LEN * 40 * 64) / 256, 256, 0, stream>>>(qkv, QS, ct, st, 40);

  transpose_bf16_k<<<dim3(KVD / 32, S_LEN / 32), dim3(32, 8), 0, stream>>>(
      qkv + 5120, vtg, S_LEN, KVD, QS);

  attn_k<<<dim3(512), 256, 0, stream>>>(qkv, qkv + 4096, vtg, ao);

  // output projection: 128x256 2-phase counted pipeline -> grid 256 (full machine)
  gemm_wo2_k<<<dim3((S_LEN / 128) * (DIM / 256)), 512, 0, stream>>>(
      ao, woT, out, S_LEN, DIM, DIM);
}